// Round 10
// baseline (225.553 us; speedup 1.0000x reference)
//
#include <hip/hip_runtime.h>

typedef unsigned short u16t;
typedef unsigned int   u32t;
typedef float  f32x4  __attribute__((ext_vector_type(4)));
typedef float  f32x16 __attribute__((ext_vector_type(16)));
typedef __bf16 bf16x8 __attribute__((ext_vector_type(8)));
typedef u16t   u16x4  __attribute__((ext_vector_type(4)));
typedef u16t   u16x8  __attribute__((ext_vector_type(8)));

#define DM    1024
#define SEQ   2048
#define NH    16
#define HD    64
#define MROWS 8192   // B*S

static __device__ __forceinline__ u16t f2bf(float f) {
  union { __bf16 b; u16t u; } c; c.b = (__bf16)f; return c.u;
}
static __device__ __forceinline__ u32t packbf(float lo, float hi) {
  union { u16t u[2]; u32t v; } c; c.u[0] = f2bf(lo); c.u[1] = f2bf(hi); return c.v;
}
static __device__ __forceinline__ bf16x8 asbf(u16x8 v) {
  union { u16x8 u; bf16x8 b; } c; c.u = v; return c.b;
}
static __device__ __forceinline__ f32x4 f4zero() {
  f32x4 z; z[0]=0.f; z[1]=0.f; z[2]=0.f; z[3]=0.f; return z;
}
static __device__ __forceinline__ void gload16(const u16t* g, u16t* l) {
  __builtin_amdgcn_global_load_lds(
      (const __attribute__((address_space(1))) unsigned int*)g,
      (__attribute__((address_space(3))) unsigned int*)l, 16, 0, 0);
}

// ---------------- per-batch stable-partition scan ----------------
// For each batch b: unmasked key positions -> slots [0, nu), masked -> [nu, 2048).
// map[b*2048+s]   = destination slot (global row index) for source key s,
// cmask[slot]     = 1 if slot < nu else 0 (int, slot order, for V-proj epilogue),
// cmf[slot]       = same as f32 (for attn's tail-tile exp masking),
// ntl[b]          = ceil(nu/64) = number of 64-key attn tiles containing live keys.
__global__ __launch_bounds__(256) void scan_kernel(
    const int* __restrict__ msk, int* __restrict__ map,
    int* __restrict__ cmask, float* __restrict__ cmf, int* __restrict__ ntl)
{
  const int b = blockIdx.x, t = threadIdx.x;
  const int lane = t & 63, w = t >> 6;
  const int base = b * 2048 + t * 8;
  int4 a0 = ((const int4*)(msk + base))[0];
  int4 a1 = ((const int4*)(msk + base))[1];
  int mv[8] = { a0.x, a0.y, a0.z, a0.w, a1.x, a1.y, a1.z, a1.w };
  int ps = 0;
#pragma unroll
  for (int i = 0; i < 8; i++) ps += mv[i];
  int sc = ps;                       // inclusive scan of per-thread sums
#pragma unroll
  for (int d = 1; d < 64; d <<= 1) {
    int o = __shfl_up(sc, d, 64);
    if (lane >= d) sc += o;
  }
  __shared__ int wsum[4];
  if (lane == 63) wsum[w] = sc;
  __syncthreads();
  int nu = wsum[0] + wsum[1] + wsum[2] + wsum[3];
  int woff = 0;
  for (int i = 0; i < w; i++) woff += wsum[i];
  int u = woff + sc - ps;            // unmasked count before this thread's first elem
#pragma unroll
  for (int i = 0; i < 8; i++) {
    int s = t * 8 + i;
    int slot = mv[i] ? u : nu + (s - u);
    map[b * 2048 + s] = b * 2048 + slot;
    u += mv[i];
  }
#pragma unroll
  for (int i = 0; i < 8; i++) {
    int s = t * 8 + i;
    int live = s < nu ? 1 : 0;
    cmask[b * 2048 + s] = live;
    cmf[b * 2048 + s] = (float)live;
  }
  if (t == 0) ntl[b] = (nu + 63) >> 6;
}

// ---------------- bf16 conversion prepass (bandwidth-bound) ----------------
// K and V input rows are written PERMUTED (stable partition by mask): each 2KB
// row lands at map[row]. Stores stay wave-coalesced (row-granular scatter only).
// Rows whose destination slot lies beyond L[b] = ceil(ntl*64/128)*128 are read
// by NO downstream block (projection early-exit) -> skip load+store entirely.
__global__ __launch_bounds__(256) void cvt_kernel(
    const float* __restrict__ q, const float* __restrict__ k, const float* __restrict__ v,
    const float* __restrict__ wq, const float* __restrict__ wk,
    const float* __restrict__ wv, const float* __restrict__ wo,
    const int* __restrict__ map, const int* __restrict__ ntl,
    u16t* qx, u16t* kx, u16t* vx,
    u16t* wqb, u16t* wkb, u16t* wvb, u16t* wob)
{
  long c = (long)blockIdx.x * 256 + threadIdx.x;
  const float* s; u16t* d; long o; bool perm = false;
  if (c < 2097152L)      { s = q; d = qx; o = c; }
  else if (c < 4194304L) { s = k; d = kx; o = c - 2097152L; perm = true; }
  else if (c < 6291456L) { s = v; d = vx; o = c - 4194304L; perm = true; }
  else {
    long wc_ = c - 6291456L;
    int wi = (int)(wc_ >> 18); o = wc_ & 262143L;
    s = wi == 0 ? wq : wi == 1 ? wk : wi == 2 ? wv : wo;
    d = wi == 0 ? wqb : wi == 1 ? wkb : wi == 2 ? wvb : wob;
  }
  long od = o;
  if (perm) {
    long dst = (long)map[o >> 8];          // 256 chunks of 4 elems per row
    int slot = (int)(dst & 2047);
    int bb = (int)(dst >> 11);
    int L = ((ntl[bb] << 6) + 127) & ~127; // proj blocks touch rows < L only
    if (slot >= L) return;                 // dead slot: nobody reads it
    od = dst * 256 + (o & 255);
  }
  f32x4 x = *(const f32x4*)(s + o * 4);
  u16x4 y; y[0]=f2bf(x[0]); y[1]=f2bf(x[1]); y[2]=f2bf(x[2]); y[3]=f2bf(x[3]);
  *(u16x4*)(d + od * 4) = y;
}

// ---------------- all-bf16 128x128 GEMM, C[m][n] = sum_k A[m][k]*W[n][k] ----------------
// LDS tiles are passed IN from the __global__ wrapper: declaring them inside this
// (multiply-instantiated) function made hipcc allocate one 32KB block PER template
// instantiation -- projs3 carried 64KB (R5 counters: LDS_Block_Size 65536,
// occupancy 13%, everything else idle). One shared allocation restores 4-5
// blocks/CU so co-resident blocks hide each other's barrier drains (m114).
template<int EPI, int MASKC>
__device__ __forceinline__ void gemm_bf(u16t* __restrict__ As, u16t* __restrict__ Bs,
                                        const u16t* __restrict__ A, const u16t* __restrict__ W,
                                        void* Op, const float* __restrict__ Rp, long ldc,
                                        const int* __restrict__ Mp, float oscale,
                                        long bM, long bN)
{
  const int t = threadIdx.x;
  const int lane = t & 63;
  const int w = t >> 6;
  const int wr = w >> 1, wc = w & 1;
  const int l15 = lane & 15, lhi = lane >> 4;

  f32x4 acc[4][4];
#pragma unroll
  for (int i = 0; i < 4; i++)
#pragma unroll
    for (int j = 0; j < 4; j++) acc[i][j] = f4zero();

  auto stg = [&](int buf, int k0) {
#pragma unroll
    for (int i = 0; i < 2; i++) {
      int idx = i * 256 + t;            // 512 chunks of 16B
      int row = idx >> 2, c4 = idx & 3;
      int ek = (c4 ^ (row & 3)) * 8;    // inverse-swizzled source column
      gload16(A + (bM + row) * (long)DM + k0 + ek, As + buf * 4096 + (i * 256 + w * 64) * 8);
      gload16(W + (bN + row) * (long)DM + k0 + ek, Bs + buf * 4096 + (i * 256 + w * 64) * 8);
    }
  };

  stg(0, 0);
  __syncthreads();
  int cur = 0;

  for (int k0 = 0; k0 < DM; k0 += 32) {
    if (k0 + 32 < DM) stg(cur ^ 1, k0 + 32);

    u16x8 af[4], bfv[4];
#pragma unroll
    for (int i = 0; i < 4; i++) {
      int ra = wr * 64 + i * 16 + l15;
      af[i]  = *(const u16x8*)((const char*)(As + cur * 4096) + ra * 64 + ((lhi ^ (ra & 3)) * 16));
      int rb = wc * 64 + i * 16 + l15;
      bfv[i] = *(const u16x8*)((const char*)(Bs + cur * 4096) + rb * 64 + ((lhi ^ (rb & 3)) * 16));
    }
#pragma unroll
    for (int i = 0; i < 4; i++)
#pragma unroll
      for (int j = 0; j < 4; j++)
        acc[i][j] = __builtin_amdgcn_mfma_f32_16x16x32_bf16(asbf(af[i]), asbf(bfv[j]), acc[i][j], 0, 0, 0);

    __syncthreads();
    cur ^= 1;
  }

#pragma unroll
  for (int i = 0; i < 4; i++) {
    long row0 = bM + wr * 64 + i * 16 + lhi * 4;
#pragma unroll
    for (int j = 0; j < 4; j++) {
      long col = bN + wc * 64 + j * 16 + l15;
      float mc = MASKC ? (float)Mp[col] * oscale : oscale;
#pragma unroll
      for (int r = 0; r < 4; r++) {
        long off = (row0 + r) * ldc + col;
        if (EPI == 0) ((u16t*)Op)[off] = f2bf(acc[i][j][r] * mc);
        else          ((float*)Op)[off] = acc[i][j][r] + Rp[off];
      }
    }
  }
}

#define SCLQ 0.1803368801111204f   // (1/sqrt(HD)) * log2(e): Q projection pre-scale (log2 domain)
#define GEMM_LDS_DECL  __shared__ u16t As[2][128 * 32]; __shared__ u16t Bs[2][128 * 32]

// V^T projection runs BEFORE qkproj in the FALLBACK path (qb aliases vx there).
// Inputs vx/kx already row-compacted; Mp = slot-ordered compacted mask.
// Early-exit: column blocks entirely beyond the live-tile boundary are dead.
__global__ __launch_bounds__(256) void vproj_t_kernel(
    const u16t* wvb, const u16t* vx, u16t* vtb, const int* cmask, const int* ntl)
{
  GEMM_LDS_DECL;
  long bN = (long)blockIdx.y * 128;
  if ((int)(bN & 2047) >= (ntl[bN >> 11] << 6)) return;
  gemm_bf<0, 1>(&As[0][0], &Bs[0][0], wvb, vx, vtb, nullptr, (long)MROWS, cmask, 1.0f,
                (long)blockIdx.x * 128, bN);
}

__global__ __launch_bounds__(256) void qkproj_kernel(
    const u16t* qx, const u16t* kx, const u16t* wqb, const u16t* wkb,
    u16t* qb, u16t* kbp, const int* ntl)
{
  GEMM_LDS_DECL;
  int z = blockIdx.z;
  if (z == 0)
    gemm_bf<0, 0>(&As[0][0], &Bs[0][0], qx, wqb, qb, nullptr, DM, nullptr, SCLQ,
                  (long)blockIdx.x * 128, (long)blockIdx.y * 128);
  else {
    long bM = (long)blockIdx.x * 128;
    if ((int)(bM & 2047) >= (ntl[bM >> 11] << 6)) return;
    gemm_bf<0, 0>(&As[0][0], &Bs[0][0], kx, wkb, kbp, nullptr, DM, nullptr, 1.0f,
                  bM, (long)blockIdx.y * 128);
  }
}

// Merged 3-projection dispatch -- ONLY legal when qb is a dedicated buffer
// (no vx alias; R7's race). z=0: V^T (masked), z=1: Q (scaled), z=2: K.
// K rows / V^T cols beyond each batch's live-tile boundary are read by nobody
// (attn visits ntl[b] tiles) -> early-exit those blocks.
__global__ __launch_bounds__(256) void projs3_kernel(
    const u16t* qx, const u16t* kx, const u16t* vx,
    const u16t* wqb, const u16t* wkb, const u16t* wvb,
    u16t* qb, u16t* kbp, u16t* vtb, const int* cmask, const int* ntl)
{
  GEMM_LDS_DECL;
  int z = blockIdx.z;
  if (z == 0) {
    long bN = (long)blockIdx.x * 128;
    if ((int)(bN & 2047) >= (ntl[bN >> 11] << 6)) return;
    gemm_bf<0, 1>(&As[0][0], &Bs[0][0], wvb, vx, vtb, nullptr, (long)MROWS, cmask, 1.0f,
                  (long)blockIdx.y * 128, bN);
  } else if (z == 1) {
    gemm_bf<0, 0>(&As[0][0], &Bs[0][0], qx, wqb, qb, nullptr, DM, nullptr, SCLQ,
                  (long)blockIdx.x * 128, (long)blockIdx.y * 128);
  } else {
    long bM = (long)blockIdx.x * 128;
    if ((int)(bM & 2047) >= (ntl[bM >> 11] << 6)) return;
    gemm_bf<0, 0>(&As[0][0], &Bs[0][0], kx, wkb, kbp, nullptr, DM, nullptr, 1.0f,
                  bM, (long)blockIdx.y * 128);
  }
}

__global__ __launch_bounds__(256) void outproj_gemm_kernel(
    const u16t* A, const u16t* Wo, float* O, const float* resid)
{
  GEMM_LDS_DECL;
  gemm_bf<1, 0>(&As[0][0], &Bs[0][0], A, Wo, O, resid, DM, nullptr, 1.0f,
                (long)blockIdx.x * 128, (long)blockIdx.y * 128);
}

// ---------------- flash attention: 32x32 swapped-QK, in-register softmax ----------------
// Keys are stable-partitioned per batch (unmasked first); only ceil(nu/64) tiles are
// visited. NO max-tracking (R5, shift-invariance + bounded scores). Mask machinery
// hoisted off the per-tile path (R9: ones-fragment lacc + tail-tile f32 masking).
// R10 (m169 precedent, Common-mistake #7): V is NOT LDS-staged -- each block's V^T
// slice (139KB) is L2-resident (16 q-tile blocks share it), so staging was pure
// overhead: it doubled the barrier's stage-drain, doubled LDS (32KB), and carried
// half the 4-way bank-conflicted ds_reads. V is now read directly from global into
// registers with a rolling 1-ahead prefetch: ks=0 pair issues BEFORE QK (full-QK
// latency cover); ks+1 issues at the top of PV iter ks (MFMA-chain cover).
// Address map verified identical to the old swizzle-undone LDS path:
//   vt[(h*64 + db*32 + l31)*MROWS + b*SEQ + kt0 + ks*16 + hi*8].
// K stays double-buffered in LDS (16KB).
__global__ __launch_bounds__(256) void attn_kernel(
    const u16t* __restrict__ qb, const u16t* __restrict__ kb,
    const u16t* __restrict__ vt, const float* __restrict__ cmf,
    const int* __restrict__ ntl, u16t* __restrict__ ob)
{
  __shared__ u16t Kt[2][64 * 64];
  const int t = threadIdx.x;
  const int lane = t & 63, wv = t >> 6;
  const int l31 = lane & 31, hi = lane >> 5;
  const int bh = blockIdx.x, qt = blockIdx.y;
  const int b = bh >> 4, h = bh & 15;
  const int q0 = qt * 128;
  const int ktend = ntl[b] << 6;

  u16x8 qf[4];
  {
    long qrow = (long)b * SEQ + q0 + wv * 32 + l31;
#pragma unroll
    for (int ds = 0; ds < 4; ds++)
      qf[ds] = *(const u16x8*)(qb + qrow * (long)DM + h * HD + ds * 16 + hi * 8);
  }

  // tile-invariant LDS read offsets (K only)
  const int swz = (l31 & 7) << 4;
  const int rowbase = l31 * 128;
  int colX[4];
#pragma unroll
  for (int c = 0; c < 4; c++) colX[c] = rowbase + ((c * 32 + hi * 16) ^ swz);

  // all-ones bf16 B-fragment for the denominator MFMA
  u16x8 onesf;
#pragma unroll
  for (int j = 0; j < 8; j++) onesf[j] = 0x3F80;

  f32x16 oacc[2], lacc, z16;
#pragma unroll
  for (int r = 0; r < 16; r++) { oacc[0][r] = 0.f; oacc[1][r] = 0.f; lacc[r] = 0.f; z16[r] = 0.f; }

  // per-thread K stage sources (advanced by constant stride each stage call)
  int idx0 = t, idx1 = t + 256;
  int row0 = idx0 >> 3, ek0 = ((idx0 & 7) * 8) ^ ((row0 & 7) << 3);
  int row1 = idx1 >> 3, ek1 = ((idx1 & 7) * 8) ^ ((row1 & 7) << 3);
  const u16t* gk0 = kb + ((long)b * SEQ + row0) * (long)DM + h * HD + ek0;
  const u16t* gk1 = kb + ((long)b * SEQ + row1) * (long)DM + h * HD + ek1;

  auto stage = [&](int buf) {
    gload16(gk0, &Kt[buf][(wv * 64) * 8]);
    gload16(gk1, &Kt[buf][(256 + wv * 64) * 8]);
    gk0 += 64 * DM; gk1 += 64 * DM;
  };

  // V direct-from-global per-lane row pointers (db = 0,1 -> d = db*32 + l31)
  const u16t* gvd0 = vt + ((long)h * HD + l31) * (long)MROWS + (long)b * SEQ + hi * 8;
  const u16t* gvd1 = gvd0 + 32L * (long)MROWS;

  stage(0);
  __syncthreads();
  int cur = 0;

  for (int kt0 = 0; kt0 < ktend; kt0 += 64) {
    const u16t* K0 = Kt[cur];
    const bool more = kt0 + 64 < ktend;

    // earliest issue: V pair for ks=0 (covered by the whole QK phase)
    u16x8 vr0 = *(const u16x8*)(gvd0 + kt0);
    u16x8 vr1 = *(const u16x8*)(gvd1 + kt0);

    f32x16 st[2];
    __builtin_amdgcn_s_setprio(1);
#pragma unroll
    for (int ds = 0; ds < 4; ds++) {
#pragma unroll
      for (int kbi = 0; kbi < 2; kbi++) {
        u16x8 kf = *(const u16x8*)((const char*)K0 + kbi * 4096 + colX[ds]);
        st[kbi] = __builtin_amdgcn_mfma_f32_32x32x16_bf16(asbf(kf), asbf(qf[ds]),
                                                          ds == 0 ? z16 : st[kbi], 0, 0, 0);
      }
    }
    __builtin_amdgcn_s_setprio(0);

    // stage next K tile AFTER QK issue (off the ds_read critical path)
    if (more) stage(cur ^ 1);

    // tail tile only: per-key f32 masks, laid out to match e_j <-> key mapping.
    // group g = ks = kbi*2+s; ma_g covers keys base+{0..3}, mb_g keys base+{8..11},
    // base = kt0 + kbi*32 + 16s + 4hi.
    f32x4 ma0, mb0, ma1, mb1, ma2, mb2, ma3, mb3;
    if (!more) {
      const float* mfp = cmf + (long)b * SEQ + kt0 + 4 * hi;
      ma0 = *(const f32x4*)(mfp + 0);  mb0 = *(const f32x4*)(mfp + 8);
      ma1 = *(const f32x4*)(mfp + 16); mb1 = *(const f32x4*)(mfp + 24);
      ma2 = *(const f32x4*)(mfp + 32); mb2 = *(const f32x4*)(mfp + 40);
      ma3 = *(const f32x4*)(mfp + 48); mb3 = *(const f32x4*)(mfp + 56);
    }

    // PV with sm-split: exp of each 8-value group computed just before its MFMAs,
    // so trans-pipe exp of group ks+1 overlaps matrix-pipe MFMAs of group ks.
    __builtin_amdgcn_s_setprio(1);
#pragma unroll
    for (int ks = 0; ks < 4; ks++) {
      const int kbi = ks >> 1, s = ks & 1;
      // consume current V pair; issue next pair (1-ahead rolling prefetch)
      u16x8 vc0 = vr0, vc1 = vr1;
      if (ks < 3) {
        vr0 = *(const u16x8*)(gvd0 + kt0 + (ks + 1) * 16);
        vr1 = *(const u16x8*)(gvd1 + kt0 + (ks + 1) * 16);
      }
      float e0 = __builtin_amdgcn_exp2f(st[kbi][8*s+0]);
      float e1 = __builtin_amdgcn_exp2f(st[kbi][8*s+1]);
      float e2 = __builtin_amdgcn_exp2f(st[kbi][8*s+2]);
      float e3 = __builtin_amdgcn_exp2f(st[kbi][8*s+3]);
      float e4 = __builtin_amdgcn_exp2f(st[kbi][8*s+4]);
      float e5 = __builtin_amdgcn_exp2f(st[kbi][8*s+5]);
      float e6 = __builtin_amdgcn_exp2f(st[kbi][8*s+6]);
      float e7 = __builtin_amdgcn_exp2f(st[kbi][8*s+7]);
      if (!more) {  // tail: zero masked keys' P exactly (x1.0 / x0.0)
        f32x4 ma = ks == 0 ? ma0 : ks == 1 ? ma1 : ks == 2 ? ma2 : ma3;
        f32x4 mb = ks == 0 ? mb0 : ks == 1 ? mb1 : ks == 2 ? mb2 : mb3;
        e0 *= ma[0]; e1 *= ma[1]; e2 *= ma[2]; e3 *= ma[3];
        e4 *= mb[0]; e5 *= mb[1]; e6 *= mb[2]; e7 *= mb[3];
      }
      // permlane32_swap(x, y): x.hi32-lanes <-> y.lo32-lanes. x = a-pack, y = b-pack.
      // Verified identical to R6's shfl_xor+select path (R10/R12 pass).
      u32t x0 = packbf(e0, e1);
      u32t y0 = packbf(e4, e5);
      u32t x1 = packbf(e2, e3);
      u32t y1 = packbf(e6, e7);
      asm("v_permlane32_swap_b32 %0, %1" : "+v"(x0), "+v"(y0));
      asm("v_permlane32_swap_b32 %0, %1" : "+v"(x1), "+v"(y1));
      union { u32t u[4]; u16x8 v; } pf;
      pf.u[0] = x0; pf.u[1] = x1; pf.u[2] = y0; pf.u[3] = y1;
      bf16x8 pa = asbf(pf.v);

      lacc = __builtin_amdgcn_mfma_f32_32x32x16_bf16(pa, asbf(onesf), lacc, 0, 0, 0);
      oacc[0] = __builtin_amdgcn_mfma_f32_32x32x16_bf16(pa, asbf(vc0), oacc[0], 0, 0, 0);
      oacc[1] = __builtin_amdgcn_mfma_f32_32x32x16_bf16(pa, asbf(vc1), oacc[1], 0, 0, 0);
    }
    __builtin_amdgcn_s_setprio(0);

    __syncthreads();   // drains K stage loads + publishes next buffer
    cur ^= 1;
  }

#pragma unroll
  for (int r = 0; r < 16; r++) {
    float inv = 1.0f / lacc[r];
    long s = (long)b * SEQ + q0 + wv * 32 + (r & 3) + 8 * (r >> 2) + 4 * hi;
#pragma unroll
    for (int db = 0; db < 2; db++)
      ob[s * (long)DM + h * HD + db * 32 + l31] = f2bf(oacc[db][r] * inv);
  }
}

// ---------------- layernorm (in-place) ----------------
__global__ __launch_bounds__(256) void ln_kernel(
    const float* __restrict__ x, const float* __restrict__ gam,
    const float* __restrict__ bet, float* __restrict__ out)
{
  __shared__ float red[8];
  const int row = blockIdx.x, t = threadIdx.x;
  const int w = t >> 6, lane = t & 63;
  const float* xr = x + (long)row * DM;
  f32x4 v = *(const f32x4*)(xr + t * 4);
  float s  = v[0] + v[1] + v[2] + v[3];
  float s2 = v[0]*v[0] + v[1]*v[1] + v[2]*v[2] + v[3]*v[3];
#pragma unroll
  for (int d = 1; d < 64; d <<= 1) {
    s  += __shfl_xor(s, d, 64);
    s2 += __shfl_xor(s2, d, 64);
  }
  if (lane == 0) { red[w] = s; red[4 + w] = s2; }
  __syncthreads();
  s  = red[0] + red[1] + red[2] + red[3];
  s2 = red[4] + red[5] + red[6] + red[7];
  float mu  = s * (1.f / DM);
  float var = s2 * (1.f / DM) - mu * mu;
  float rstd = rsqrtf(var + 1e-5f);
  f32x4 g = *(const f32x4*)(gam + t * 4);
  f32x4 bb = *(const f32x4*)(bet + t * 4);
  f32x4 o;
#pragma unroll
  for (int j = 0; j < 4; j++) o[j] = (v[j] - mu) * rstd * g[j] + bb[j];
  *(f32x4*)(out + (long)row * DM + t * 4) = o;
}

extern "C" void kernel_launch(void* const* d_in, const int* in_sizes, int n_in,
                              void* d_out, int out_size, void* d_ws, size_t ws_size,
                              hipStream_t stream)
{
  const float* query = (const float*)d_in[0];
  const float* key   = (const float*)d_in[1];
  const float* value = (const float*)d_in[2];
  const int*   msk   = (const int*)d_in[3];
  const float* Wq    = (const float*)d_in[4];
  const float* Wk    = (const float*)d_in[5];
  const float* Wv    = (const float*)d_in[6];
  const float* Wo    = (const float*)d_in[7];
  const float* gam   = (const float*)d_in[8];
  const float* bet   = (const float*)d_in[9];
  float* out = (float*)d_out;

  const long SZ = (long)MROWS * DM;     // 8.4M elements
  const long WS = (long)DM * DM;        // 1M elements
  u16t* qx  = (u16t*)d_out;             // bf16 query [8192][1024] (d_out as scratch)
  u16t* kx  = qx + SZ;                  // bf16 key (row-compacted)
  u16t* vx  = (u16t*)d_ws;              // bf16 value (row-compacted)
  u16t* vtb = vx + SZ;                  // bf16 masked V^T [1024][8192] (compacted cols)
  u16t* kbp = vtb + SZ;                 // bf16 projected k (compacted rows)
  u16t* wqb = kbp + SZ;                 // bf16 weights
  u16t* wkb = wqb + WS;
  u16t* wvb = wkb + WS;
  u16t* wob = wvb + WS;
  int*  map = (int*)(wob + WS);         // stable-partition destination rows [8192]
  int*  cmask = map + 8192;             // int compacted mask [8192] (slot order)
  float* cmf = (float*)(cmask + 8192);  // f32 compacted mask [8192] (attn tail)
  int*  ntl = (int*)(cmf + 8192);       // per-batch live-tile counts [4]
  u16t* ws_end = (u16t*)(ntl + 4);
  // If ws has room, give projected-q its own buffer -> all three projections
  // become independent and merge into ONE dispatch (no vx alias race).
  size_t used_bytes = (size_t)((char*)ws_end - (char*)d_ws);
  bool big = ws_size >= used_bytes + (size_t)SZ * 2;
  u16t* qb = big ? ws_end : vx;         // fallback: qb aliases vx (R13 path)
  u16t* ab = qb;                        // attn out overwrites qb
  float* xres = out;

  scan_kernel<<<dim3(4), 256, 0, stream>>>(msk, map, cmask, cmf, ntl);
  cvt_kernel<<<dim3(28672), 256, 0, stream>>>(query, key, value, Wq, Wk, Wv, Wo, map, ntl,
                                              qx, kx, vx, wqb, wkb, wvb, wob);
  if (big) {
    projs3_kernel<<<dim3(64, 8, 3), 256, 0, stream>>>(qx, kx, vx, wqb, wkb, wvb,
                                                      qb, kbp, vtb, cmask, ntl);
  } else {
    vproj_t_kernel<<<dim3(8, 64), 256, 0, stream>>>(wvb, vx, vtb, cmask, ntl); // reads vx
    qkproj_kernel<<<dim3(64, 8, 2), 256, 0, stream>>>(qx, kx, wqb, wkb, qb, kbp, ntl);
  }
  attn_kernel<<<dim3(64, 16), 256, 0, stream>>>(qb, kbp, vtb, cmf, ntl, ab);
  outproj_gemm_kernel<<<dim3(64, 8), 256, 0, stream>>>(ab, wob, xres, query);
  ln_kernel<<<dim3(MROWS), 256, 0, stream>>>(xres, gam, bet, out);
}

// Round 11
// 202.549 us; speedup vs baseline: 1.1136x; 1.1136x over previous
//
#include <hip/hip_runtime.h>

typedef unsigned short u16t;
typedef unsigned int   u32t;
typedef float  f32x4  __attribute__((ext_vector_type(4)));
typedef float  f32x16 __attribute__((ext_vector_type(16)));
typedef __bf16 bf16x8 __attribute__((ext_vector_type(8)));
typedef u16t   u16x4  __attribute__((ext_vector_type(4)));
typedef u16t   u16x8  __attribute__((ext_vector_type(8)));

#define DM    1024
#define SEQ   2048
#define NH    16
#define HD    64
#define MROWS 8192   // B*S

static __device__ __forceinline__ u16t f2bf(float f) {
  union { __bf16 b; u16t u; } c; c.b = (__bf16)f; return c.u;
}
static __device__ __forceinline__ u32t packbf(float lo, float hi) {
  union { u16t u[2]; u32t v; } c; c.u[0] = f2bf(lo); c.u[1] = f2bf(hi); return c.v;
}
static __device__ __forceinline__ bf16x8 asbf(u16x8 v) {
  union { u16x8 u; bf16x8 b; } c; c.u = v; return c.b;
}
static __device__ __forceinline__ f32x4 f4zero() {
  f32x4 z; z[0]=0.f; z[1]=0.f; z[2]=0.f; z[3]=0.f; return z;
}
static __device__ __forceinline__ void gload16(const u16t* g, u16t* l) {
  __builtin_amdgcn_global_load_lds(
      (const __attribute__((address_space(1))) unsigned int*)g,
      (__attribute__((address_space(3))) unsigned int*)l, 16, 0, 0);
}

// ---------------- per-batch stable-partition scan ----------------
// For each batch b: unmasked key positions -> slots [0, nu), masked -> [nu, 2048).
// map[b*2048+s]   = destination slot (global row index) for source key s,
// cmask[slot]     = 1 if slot < nu else 0 (int, slot order, for V-proj epilogue),
// cmf[slot]       = same as f32 (for attn's tail-tile exp masking),
// ntl[b]          = ceil(nu/64) = number of 64-key attn tiles containing live keys.
__global__ __launch_bounds__(256) void scan_kernel(
    const int* __restrict__ msk, int* __restrict__ map,
    int* __restrict__ cmask, float* __restrict__ cmf, int* __restrict__ ntl)
{
  const int b = blockIdx.x, t = threadIdx.x;
  const int lane = t & 63, w = t >> 6;
  const int base = b * 2048 + t * 8;
  int4 a0 = ((const int4*)(msk + base))[0];
  int4 a1 = ((const int4*)(msk + base))[1];
  int mv[8] = { a0.x, a0.y, a0.z, a0.w, a1.x, a1.y, a1.z, a1.w };
  int ps = 0;
#pragma unroll
  for (int i = 0; i < 8; i++) ps += mv[i];
  int sc = ps;                       // inclusive scan of per-thread sums
#pragma unroll
  for (int d = 1; d < 64; d <<= 1) {
    int o = __shfl_up(sc, d, 64);
    if (lane >= d) sc += o;
  }
  __shared__ int wsum[4];
  if (lane == 63) wsum[w] = sc;
  __syncthreads();
  int nu = wsum[0] + wsum[1] + wsum[2] + wsum[3];
  int woff = 0;
  for (int i = 0; i < w; i++) woff += wsum[i];
  int u = woff + sc - ps;            // unmasked count before this thread's first elem
#pragma unroll
  for (int i = 0; i < 8; i++) {
    int s = t * 8 + i;
    int slot = mv[i] ? u : nu + (s - u);
    map[b * 2048 + s] = b * 2048 + slot;
    u += mv[i];
  }
#pragma unroll
  for (int i = 0; i < 8; i++) {
    int s = t * 8 + i;
    int live = s < nu ? 1 : 0;
    cmask[b * 2048 + s] = live;
    cmf[b * 2048 + s] = (float)live;
  }
  if (t == 0) ntl[b] = (nu + 63) >> 6;
}

// ---------------- bf16 conversion prepass (bandwidth-bound) ----------------
// K and V input rows are written PERMUTED (stable partition by mask): each 2KB
// row lands at map[row]. Stores stay wave-coalesced (row-granular scatter only).
// Rows whose destination slot lies beyond L[b] = ceil(ntl*64/128)*128 are read
// by NO downstream block (projection early-exit) -> skip load+store entirely.
__global__ __launch_bounds__(256) void cvt_kernel(
    const float* __restrict__ q, const float* __restrict__ k, const float* __restrict__ v,
    const float* __restrict__ wq, const float* __restrict__ wk,
    const float* __restrict__ wv, const float* __restrict__ wo,
    const int* __restrict__ map, const int* __restrict__ ntl,
    u16t* qx, u16t* kx, u16t* vx,
    u16t* wqb, u16t* wkb, u16t* wvb, u16t* wob)
{
  long c = (long)blockIdx.x * 256 + threadIdx.x;
  const float* s; u16t* d; long o; bool perm = false;
  if (c < 2097152L)      { s = q; d = qx; o = c; }
  else if (c < 4194304L) { s = k; d = kx; o = c - 2097152L; perm = true; }
  else if (c < 6291456L) { s = v; d = vx; o = c - 4194304L; perm = true; }
  else {
    long wc_ = c - 6291456L;
    int wi = (int)(wc_ >> 18); o = wc_ & 262143L;
    s = wi == 0 ? wq : wi == 1 ? wk : wi == 2 ? wv : wo;
    d = wi == 0 ? wqb : wi == 1 ? wkb : wi == 2 ? wvb : wob;
  }
  long od = o;
  if (perm) {
    long dst = (long)map[o >> 8];          // 256 chunks of 4 elems per row
    int slot = (int)(dst & 2047);
    int bb = (int)(dst >> 11);
    int L = ((ntl[bb] << 6) + 127) & ~127; // proj blocks touch rows < L only
    if (slot >= L) return;                 // dead slot: nobody reads it
    od = dst * 256 + (o & 255);
  }
  f32x4 x = *(const f32x4*)(s + o * 4);
  u16x4 y; y[0]=f2bf(x[0]); y[1]=f2bf(x[1]); y[2]=f2bf(x[2]); y[3]=f2bf(x[3]);
  *(u16x4*)(d + od * 4) = y;
}

// ---------------- all-bf16 128x128 GEMM, C[m][n] = sum_k A[m][k]*W[n][k] ----------------
// LDS tiles are passed IN from the __global__ wrapper: declaring them inside this
// (multiply-instantiated) function made hipcc allocate one 32KB block PER template
// instantiation -- projs3 carried 64KB (R5 counters: LDS_Block_Size 65536,
// occupancy 13%, everything else idle). One shared allocation restores 4-5
// blocks/CU so co-resident blocks hide each other's barrier drains (m114).
template<int EPI, int MASKC>
__device__ __forceinline__ void gemm_bf(u16t* __restrict__ As, u16t* __restrict__ Bs,
                                        const u16t* __restrict__ A, const u16t* __restrict__ W,
                                        void* Op, const float* __restrict__ Rp, long ldc,
                                        const int* __restrict__ Mp, float oscale,
                                        long bM, long bN)
{
  const int t = threadIdx.x;
  const int lane = t & 63;
  const int w = t >> 6;
  const int wr = w >> 1, wc = w & 1;
  const int l15 = lane & 15, lhi = lane >> 4;

  f32x4 acc[4][4];
#pragma unroll
  for (int i = 0; i < 4; i++)
#pragma unroll
    for (int j = 0; j < 4; j++) acc[i][j] = f4zero();

  auto stg = [&](int buf, int k0) {
#pragma unroll
    for (int i = 0; i < 2; i++) {
      int idx = i * 256 + t;            // 512 chunks of 16B
      int row = idx >> 2, c4 = idx & 3;
      int ek = (c4 ^ (row & 3)) * 8;    // inverse-swizzled source column
      gload16(A + (bM + row) * (long)DM + k0 + ek, As + buf * 4096 + (i * 256 + w * 64) * 8);
      gload16(W + (bN + row) * (long)DM + k0 + ek, Bs + buf * 4096 + (i * 256 + w * 64) * 8);
    }
  };

  stg(0, 0);
  __syncthreads();
  int cur = 0;

  for (int k0 = 0; k0 < DM; k0 += 32) {
    if (k0 + 32 < DM) stg(cur ^ 1, k0 + 32);

    u16x8 af[4], bfv[4];
#pragma unroll
    for (int i = 0; i < 4; i++) {
      int ra = wr * 64 + i * 16 + l15;
      af[i]  = *(const u16x8*)((const char*)(As + cur * 4096) + ra * 64 + ((lhi ^ (ra & 3)) * 16));
      int rb = wc * 64 + i * 16 + l15;
      bfv[i] = *(const u16x8*)((const char*)(Bs + cur * 4096) + rb * 64 + ((lhi ^ (rb & 3)) * 16));
    }
#pragma unroll
    for (int i = 0; i < 4; i++)
#pragma unroll
      for (int j = 0; j < 4; j++)
        acc[i][j] = __builtin_amdgcn_mfma_f32_16x16x32_bf16(asbf(af[i]), asbf(bfv[j]), acc[i][j], 0, 0, 0);

    __syncthreads();
    cur ^= 1;
  }

#pragma unroll
  for (int i = 0; i < 4; i++) {
    long row0 = bM + wr * 64 + i * 16 + lhi * 4;
#pragma unroll
    for (int j = 0; j < 4; j++) {
      long col = bN + wc * 64 + j * 16 + l15;
      float mc = MASKC ? (float)Mp[col] * oscale : oscale;
#pragma unroll
      for (int r = 0; r < 4; r++) {
        long off = (row0 + r) * ldc + col;
        if (EPI == 0) ((u16t*)Op)[off] = f2bf(acc[i][j][r] * mc);
        else          ((float*)Op)[off] = acc[i][j][r] + Rp[off];
      }
    }
  }
}

#define SCLQ 0.1803368801111204f   // (1/sqrt(HD)) * log2(e): Q projection pre-scale (log2 domain)
#define GEMM_LDS_DECL  __shared__ u16t As[2][128 * 32]; __shared__ u16t Bs[2][128 * 32]

// V^T projection runs BEFORE qkproj in the FALLBACK path (qb aliases vx there).
// Inputs vx/kx already row-compacted; Mp = slot-ordered compacted mask.
// Early-exit: column blocks entirely beyond the live-tile boundary are dead.
__global__ __launch_bounds__(256) void vproj_t_kernel(
    const u16t* wvb, const u16t* vx, u16t* vtb, const int* cmask, const int* ntl)
{
  GEMM_LDS_DECL;
  long bN = (long)blockIdx.y * 128;
  if ((int)(bN & 2047) >= (ntl[bN >> 11] << 6)) return;
  gemm_bf<0, 1>(&As[0][0], &Bs[0][0], wvb, vx, vtb, nullptr, (long)MROWS, cmask, 1.0f,
                (long)blockIdx.x * 128, bN);
}

__global__ __launch_bounds__(256) void qkproj_kernel(
    const u16t* qx, const u16t* kx, const u16t* wqb, const u16t* wkb,
    u16t* qb, u16t* kbp, const int* ntl)
{
  GEMM_LDS_DECL;
  int z = blockIdx.z;
  if (z == 0)
    gemm_bf<0, 0>(&As[0][0], &Bs[0][0], qx, wqb, qb, nullptr, DM, nullptr, SCLQ,
                  (long)blockIdx.x * 128, (long)blockIdx.y * 128);
  else {
    long bM = (long)blockIdx.x * 128;
    if ((int)(bM & 2047) >= (ntl[bM >> 11] << 6)) return;
    gemm_bf<0, 0>(&As[0][0], &Bs[0][0], kx, wkb, kbp, nullptr, DM, nullptr, 1.0f,
                  bM, (long)blockIdx.y * 128);
  }
}

// Merged 3-projection dispatch -- ONLY legal when qb is a dedicated buffer
// (no vx alias; R7's race). z=0: V^T (masked), z=1: Q (scaled), z=2: K.
// K rows / V^T cols beyond each batch's live-tile boundary are read by nobody
// (attn visits ntl[b] tiles) -> early-exit those blocks.
__global__ __launch_bounds__(256) void projs3_kernel(
    const u16t* qx, const u16t* kx, const u16t* vx,
    const u16t* wqb, const u16t* wkb, const u16t* wvb,
    u16t* qb, u16t* kbp, u16t* vtb, const int* cmask, const int* ntl)
{
  GEMM_LDS_DECL;
  int z = blockIdx.z;
  if (z == 0) {
    long bN = (long)blockIdx.x * 128;
    if ((int)(bN & 2047) >= (ntl[bN >> 11] << 6)) return;
    gemm_bf<0, 1>(&As[0][0], &Bs[0][0], wvb, vx, vtb, nullptr, (long)MROWS, cmask, 1.0f,
                  (long)blockIdx.y * 128, bN);
  } else if (z == 1) {
    gemm_bf<0, 0>(&As[0][0], &Bs[0][0], qx, wqb, qb, nullptr, DM, nullptr, SCLQ,
                  (long)blockIdx.x * 128, (long)blockIdx.y * 128);
  } else {
    long bM = (long)blockIdx.x * 128;
    if ((int)(bM & 2047) >= (ntl[bM >> 11] << 6)) return;
    gemm_bf<0, 0>(&As[0][0], &Bs[0][0], kx, wkb, kbp, nullptr, DM, nullptr, 1.0f,
                  bM, (long)blockIdx.y * 128);
  }
}

__global__ __launch_bounds__(256) void outproj_gemm_kernel(
    const u16t* A, const u16t* Wo, float* O, const float* resid)
{
  GEMM_LDS_DECL;
  gemm_bf<1, 0>(&As[0][0], &Bs[0][0], A, Wo, O, resid, DM, nullptr, 1.0f,
                (long)blockIdx.x * 128, (long)blockIdx.y * 128);
}

// ---------------- flash attention: 32x32 swapped-QK, in-register softmax ----------------
// Keys are stable-partitioned per batch (unmasked first); only ceil(nu/64) tiles are
// visited. NO max-tracking (R5). Mask machinery hoisted (R9: ones-fragment lacc +
// tail-tile f32 masking). V is back in LDS (R10's direct-global V regressed 38%:
// per-lane row-scattered reads touch 64 cache lines per load vs 8 coalesced).
// R11: 256-ROW Q-TILE, 512 threads / 8 waves. Per-tile K/V staging (1024 chunks)
// now serves 2x the q-rows: per-thread stage drops 4->2 loads, grid halves to
// 512 blocks (2/CU, still 16 waves/CU), K/V re-streaming and barrier count per
// q-row halve. Per-wave math (QK, softmax, PV, epilogue) byte-identical to R9;
// only wv ranges 0..7 and q0 = qt*256.
__global__ __launch_bounds__(512) void attn_kernel(
    const u16t* __restrict__ qb, const u16t* __restrict__ kb,
    const u16t* __restrict__ vt, const float* __restrict__ cmf,
    const int* __restrict__ ntl, u16t* __restrict__ ob)
{
  __shared__ u16t Kt[2][64 * 64];
  __shared__ u16t Vs[2][64 * 64];
  const int t = threadIdx.x;
  const int lane = t & 63, wv = t >> 6;        // wv 0..7
  const int l31 = lane & 31, hi = lane >> 5;
  const int bh = blockIdx.x, qt = blockIdx.y;  // grid (64, 8)
  const int b = bh >> 4, h = bh & 15;
  const int q0 = qt * 256;
  const int ktend = ntl[b] << 6;

  u16x8 qf[4];
  {
    long qrow = (long)b * SEQ + q0 + wv * 32 + l31;
#pragma unroll
    for (int ds = 0; ds < 4; ds++)
      qf[ds] = *(const u16x8*)(qb + qrow * (long)DM + h * HD + ds * 16 + hi * 8);
  }

  // tile-invariant LDS read offsets
  const int swz = (l31 & 7) << 4;
  const int rowbase = l31 * 128;
  int colX[4];
#pragma unroll
  for (int c = 0; c < 4; c++) colX[c] = rowbase + ((c * 32 + hi * 16) ^ swz);

  // all-ones bf16 B-fragment for the denominator MFMA
  u16x8 onesf;
#pragma unroll
  for (int j = 0; j < 8; j++) onesf[j] = 0x3F80;

  f32x16 oacc[2], lacc, z16;
#pragma unroll
  for (int r = 0; r < 16; r++) { oacc[0][r] = 0.f; oacc[1][r] = 0.f; lacc[r] = 0.f; z16[r] = 0.f; }

  // per-thread stage sources: 512 threads cover 512 K-chunks + 512 V-chunks
  // (1 each; chunk idx = t, row = t>>3, swizzled col = (t&7)*8 ^ ((row&7)<<3)).
  // LDS dest is wave-uniform base + lane*16B (global_load_lds rule).
  {
  }
  int srow = t >> 3, sek = ((t & 7) * 8) ^ ((srow & 7) << 3);
  const u16t* gk0 = kb + ((long)b * SEQ + srow) * (long)DM + h * HD + sek;
  const u16t* gv0 = vt + ((long)h * HD + srow) * (long)MROWS + (long)b * SEQ + sek;

  auto stage = [&](int buf) {
    gload16(gk0, &Kt[buf][(wv * 64) * 8]);
    gload16(gv0, &Vs[buf][(wv * 64) * 8]);
    gk0 += 64 * DM; gv0 += 64;
  };

  stage(0);
  __syncthreads();
  int cur = 0;

  for (int kt0 = 0; kt0 < ktend; kt0 += 64) {
    const u16t* K0 = Kt[cur];
    const u16t* V0 = Vs[cur];
    const bool more = kt0 + 64 < ktend;

    f32x16 st[2];
    __builtin_amdgcn_s_setprio(1);
#pragma unroll
    for (int ds = 0; ds < 4; ds++) {
#pragma unroll
      for (int kbi = 0; kbi < 2; kbi++) {
        u16x8 kf = *(const u16x8*)((const char*)K0 + kbi * 4096 + colX[ds]);
        st[kbi] = __builtin_amdgcn_mfma_f32_32x32x16_bf16(asbf(kf), asbf(qf[ds]),
                                                          ds == 0 ? z16 : st[kbi], 0, 0, 0);
      }
    }
    __builtin_amdgcn_s_setprio(0);

    // stage next tile AFTER QK issue (off the ds_read critical path)
    if (more) stage(cur ^ 1);

    // tail tile only: per-key f32 masks, laid out to match e_j <-> key mapping.
    // group g = ks = kbi*2+s; ma_g covers keys base+{0..3}, mb_g keys base+{8..11},
    // base = kt0 + kbi*32 + 16s + 4hi.
    f32x4 ma0, mb0, ma1, mb1, ma2, mb2, ma3, mb3;
    if (!more) {
      const float* mfp = cmf + (long)b * SEQ + kt0 + 4 * hi;
      ma0 = *(const f32x4*)(mfp + 0);  mb0 = *(const f32x4*)(mfp + 8);
      ma1 = *(const f32x4*)(mfp + 16); mb1 = *(const f32x4*)(mfp + 24);
      ma2 = *(const f32x4*)(mfp + 32); mb2 = *(const f32x4*)(mfp + 40);
      ma3 = *(const f32x4*)(mfp + 48); mb3 = *(const f32x4*)(mfp + 56);
    }

    // PV with sm-split: exp of each 8-value group computed just before its MFMAs,
    // so trans-pipe exp of group ks+1 overlaps matrix-pipe MFMAs of group ks.
    __builtin_amdgcn_s_setprio(1);
#pragma unroll
    for (int ks = 0; ks < 4; ks++) {
      const int kbi = ks >> 1, s = ks & 1;
      float e0 = __builtin_amdgcn_exp2f(st[kbi][8*s+0]);
      float e1 = __builtin_amdgcn_exp2f(st[kbi][8*s+1]);
      float e2 = __builtin_amdgcn_exp2f(st[kbi][8*s+2]);
      float e3 = __builtin_amdgcn_exp2f(st[kbi][8*s+3]);
      float e4 = __builtin_amdgcn_exp2f(st[kbi][8*s+4]);
      float e5 = __builtin_amdgcn_exp2f(st[kbi][8*s+5]);
      float e6 = __builtin_amdgcn_exp2f(st[kbi][8*s+6]);
      float e7 = __builtin_amdgcn_exp2f(st[kbi][8*s+7]);
      if (!more) {  // tail: zero masked keys' P exactly (x1.0 / x0.0)
        f32x4 ma = ks == 0 ? ma0 : ks == 1 ? ma1 : ks == 2 ? ma2 : ma3;
        f32x4 mb = ks == 0 ? mb0 : ks == 1 ? mb1 : ks == 2 ? mb2 : mb3;
        e0 *= ma[0]; e1 *= ma[1]; e2 *= ma[2]; e3 *= ma[3];
        e4 *= mb[0]; e5 *= mb[1]; e6 *= mb[2]; e7 *= mb[3];
      }
      // permlane32_swap(x, y): x.hi32-lanes <-> y.lo32-lanes. x = a-pack, y = b-pack.
      // Verified identical to R6's shfl_xor+select path (R10/R12 pass).
      u32t x0 = packbf(e0, e1);
      u32t y0 = packbf(e4, e5);
      u32t x1 = packbf(e2, e3);
      u32t y1 = packbf(e6, e7);
      asm("v_permlane32_swap_b32 %0, %1" : "+v"(x0), "+v"(y0));
      asm("v_permlane32_swap_b32 %0, %1" : "+v"(x1), "+v"(y1));
      union { u32t u[4]; u16x8 v; } pf;
      pf.u[0] = x0; pf.u[1] = x1; pf.u[2] = y0; pf.u[3] = y1;
      bf16x8 pa = asbf(pf.v);

      lacc = __builtin_amdgcn_mfma_f32_32x32x16_bf16(pa, asbf(onesf), lacc, 0, 0, 0);
#pragma unroll
      for (int db = 0; db < 2; db++) {
        u16x8 vf = *(const u16x8*)((const char*)V0 + db * 4096 + colX[ks]);
        oacc[db] = __builtin_amdgcn_mfma_f32_32x32x16_bf16(pa, asbf(vf), oacc[db], 0, 0, 0);
      }
    }
    __builtin_amdgcn_s_setprio(0);

    __syncthreads();   // drains stage loads + publishes next buffer
    cur ^= 1;
  }

#pragma unroll
  for (int r = 0; r < 16; r++) {
    float inv = 1.0f / lacc[r];
    long s = (long)b * SEQ + q0 + wv * 32 + (r & 3) + 8 * (r >> 2) + 4 * hi;
#pragma unroll
    for (int db = 0; db < 2; db++)
      ob[s * (long)DM + h * HD + db * 32 + l31] = f2bf(oacc[db][r] * inv);
  }
}

// ---------------- layernorm (in-place) ----------------
__global__ __launch_bounds__(256) void ln_kernel(
    const float* __restrict__ x, const float* __restrict__ gam,
    const float* __restrict__ bet, float* __restrict__ out)
{
  __shared__ float red[8];
  const int row = blockIdx.x, t = threadIdx.x;
  const int w = t >> 6, lane = t & 63;
  const float* xr = x + (long)row * DM;
  f32x4 v = *(const f32x4*)(xr + t * 4);
  float s  = v[0] + v[1] + v[2] + v[3];
  float s2 = v[0]*v[0] + v[1]*v[1] + v[2]*v[2] + v[3]*v[3];
#pragma unroll
  for (int d = 1; d < 64; d <<= 1) {
    s  += __shfl_xor(s, d, 64);
    s2 += __shfl_xor(s2, d, 64);
  }
  if (lane == 0) { red[w] = s; red[4 + w] = s2; }
  __syncthreads();
  s  = red[0] + red[1] + red[2] + red[3];
  s2 = red[4] + red[5] + red[6] + red[7];
  float mu  = s * (1.f / DM);
  float var = s2 * (1.f / DM) - mu * mu;
  float rstd = rsqrtf(var + 1e-5f);
  f32x4 g = *(const f32x4*)(gam + t * 4);
  f32x4 bb = *(const f32x4*)(bet + t * 4);
  f32x4 o;
#pragma unroll
  for (int j = 0; j < 4; j++) o[j] = (v[j] - mu) * rstd * g[j] + bb[j];
  *(f32x4*)(out + (long)row * DM + t * 4) = o;
}

extern "C" void kernel_launch(void* const* d_in, const int* in_sizes, int n_in,
                              void* d_out, int out_size, void* d_ws, size_t ws_size,
                              hipStream_t stream)
{
  const float* query = (const float*)d_in[0];
  const float* key   = (const float*)d_in[1];
  const float* value = (const float*)d_in[2];
  const int*   msk   = (const int*)d_in[3];
  const float* Wq    = (const float*)d_in[4];
  const float* Wk    = (const float*)d_in[5];
  const float* Wv    = (const float*)d_in[6];
  const float* Wo    = (const float*)d_in[7];
  const float* gam   = (const float*)d_in[8];
  const float* bet   = (const float*)d_in[9];
  float* out = (float*)d_out;

  const long SZ = (long)MROWS * DM;     // 8.4M elements
  const long WS = (long)DM * DM;        // 1M elements
  u16t* qx  = (u16t*)d_out;             // bf16 query [8192][1024] (d_out as scratch)
  u16t* kx  = qx + SZ;                  // bf16 key (row-compacted)
  u16t* vx  = (u16t*)d_ws;              // bf16 value (row-compacted)
  u16t* vtb = vx + SZ;                  // bf16 masked V^T [1024][8192] (compacted cols)
  u16t* kbp = vtb + SZ;                 // bf16 projected k (compacted rows)
  u16t* wqb = kbp + SZ;                 // bf16 weights
  u16t* wkb = wqb + WS;
  u16t* wvb = wkb + WS;
  u16t* wob = wvb + WS;
  int*  map = (int*)(wob + WS);         // stable-partition destination rows [8192]
  int*  cmask = map + 8192;             // int compacted mask [8192] (slot order)
  float* cmf = (float*)(cmask + 8192);  // f32 compacted mask [8192] (attn tail)
  int*  ntl = (int*)(cmf + 8192);       // per-batch live-tile counts [4]
  u16t* ws_end = (u16t*)(ntl + 4);
  // If ws has room, give projected-q its own buffer -> all three projections
  // become independent and merge into ONE dispatch (no vx alias race).
  size_t used_bytes = (size_t)((char*)ws_end - (char*)d_ws);
  bool big = ws_size >= used_bytes + (size_t)SZ * 2;
  u16t* qb = big ? ws_end : vx;         // fallback: qb aliases vx (R13 path)
  u16t* ab = qb;                        // attn out overwrites qb
  float* xres = out;

  scan_kernel<<<dim3(4), 256, 0, stream>>>(msk, map, cmask, cmf, ntl);
  cvt_kernel<<<dim3(28672), 256, 0, stream>>>(query, key, value, Wq, Wk, Wv, Wo, map, ntl,
                                              qx, kx, vx, wqb, wkb, wvb, wob);
  if (big) {
    projs3_kernel<<<dim3(64, 8, 3), 256, 0, stream>>>(qx, kx, vx, wqb, wkb, wvb,
                                                      qb, kbp, vtb, cmask, ntl);
  } else {
    vproj_t_kernel<<<dim3(8, 64), 256, 0, stream>>>(wvb, vx, vtb, cmask, ntl); // reads vx
    qkproj_kernel<<<dim3(64, 8, 2), 256, 0, stream>>>(qx, kx, wqb, wkb, qb, kbp, ntl);
  }
  attn_kernel<<<dim3(64, 8), 512, 0, stream>>>(qb, kbp, vtb, cmf, ntl, ab);
  outproj_gemm_kernel<<<dim3(64, 8), 256, 0, stream>>>(ab, wob, xres, query);
  ln_kernel<<<dim3(MROWS), 256, 0, stream>>>(xres, gam, bet, out);
}

// Round 12
// 199.333 us; speedup vs baseline: 1.1315x; 1.0161x over previous
//
#include <hip/hip_runtime.h>

typedef unsigned short u16t;
typedef unsigned int   u32t;
typedef float  f32x4  __attribute__((ext_vector_type(4)));
typedef float  f32x16 __attribute__((ext_vector_type(16)));
typedef __bf16 bf16x8 __attribute__((ext_vector_type(8)));
typedef u16t   u16x4  __attribute__((ext_vector_type(4)));
typedef u16t   u16x8  __attribute__((ext_vector_type(8)));

#define DM    1024
#define SEQ   2048
#define NH    16
#define HD    64
#define MROWS 8192   // B*S

static __device__ __forceinline__ u16t f2bf(float f) {
  union { __bf16 b; u16t u; } c; c.b = (__bf16)f; return c.u;
}
static __device__ __forceinline__ u32t packbf(float lo, float hi) {
  union { u16t u[2]; u32t v; } c; c.u[0] = f2bf(lo); c.u[1] = f2bf(hi); return c.v;
}
static __device__ __forceinline__ bf16x8 asbf(u16x8 v) {
  union { u16x8 u; bf16x8 b; } c; c.u = v; return c.b;
}
static __device__ __forceinline__ f32x4 f4zero() {
  f32x4 z; z[0]=0.f; z[1]=0.f; z[2]=0.f; z[3]=0.f; return z;
}
static __device__ __forceinline__ void gload16(const u16t* g, u16t* l) {
  __builtin_amdgcn_global_load_lds(
      (const __attribute__((address_space(1))) unsigned int*)g,
      (__attribute__((address_space(3))) unsigned int*)l, 16, 0, 0);
}

// ---------------- per-batch stable-partition scan ----------------
// For each batch b: unmasked key positions -> slots [0, nu), masked -> [nu, 2048).
// map[b*2048+s]   = destination slot (global row index) for source key s,
// cmask[slot]     = 1 if slot < nu else 0 (int, slot order, for V-proj epilogue),
// cmf[slot]       = same as f32 (for attn's tail-tile exp masking),
// ntl[b]          = ceil(nu/64) = number of 64-key attn tiles containing live keys.
__global__ __launch_bounds__(256) void scan_kernel(
    const int* __restrict__ msk, int* __restrict__ map,
    int* __restrict__ cmask, float* __restrict__ cmf, int* __restrict__ ntl)
{
  const int b = blockIdx.x, t = threadIdx.x;
  const int lane = t & 63, w = t >> 6;
  const int base = b * 2048 + t * 8;
  int4 a0 = ((const int4*)(msk + base))[0];
  int4 a1 = ((const int4*)(msk + base))[1];
  int mv[8] = { a0.x, a0.y, a0.z, a0.w, a1.x, a1.y, a1.z, a1.w };
  int ps = 0;
#pragma unroll
  for (int i = 0; i < 8; i++) ps += mv[i];
  int sc = ps;                       // inclusive scan of per-thread sums
#pragma unroll
  for (int d = 1; d < 64; d <<= 1) {
    int o = __shfl_up(sc, d, 64);
    if (lane >= d) sc += o;
  }
  __shared__ int wsum[4];
  if (lane == 63) wsum[w] = sc;
  __syncthreads();
  int nu = wsum[0] + wsum[1] + wsum[2] + wsum[3];
  int woff = 0;
  for (int i = 0; i < w; i++) woff += wsum[i];
  int u = woff + sc - ps;            // unmasked count before this thread's first elem
#pragma unroll
  for (int i = 0; i < 8; i++) {
    int s = t * 8 + i;
    int slot = mv[i] ? u : nu + (s - u);
    map[b * 2048 + s] = b * 2048 + slot;
    u += mv[i];
  }
#pragma unroll
  for (int i = 0; i < 8; i++) {
    int s = t * 8 + i;
    int live = s < nu ? 1 : 0;
    cmask[b * 2048 + s] = live;
    cmf[b * 2048 + s] = (float)live;
  }
  if (t == 0) ntl[b] = (nu + 63) >> 6;
}

// ---------------- bf16 conversion prepass (bandwidth-bound) ----------------
// K and V input rows are written PERMUTED (stable partition by mask): each 2KB
// row lands at map[row]. Stores stay wave-coalesced (row-granular scatter only).
// Rows whose destination slot lies beyond L[b] = ceil(ntl*64/128)*128 are read
// by NO downstream block (projection early-exit) -> skip load+store entirely.
__global__ __launch_bounds__(256) void cvt_kernel(
    const float* __restrict__ q, const float* __restrict__ k, const float* __restrict__ v,
    const float* __restrict__ wq, const float* __restrict__ wk,
    const float* __restrict__ wv, const float* __restrict__ wo,
    const int* __restrict__ map, const int* __restrict__ ntl,
    u16t* qx, u16t* kx, u16t* vx,
    u16t* wqb, u16t* wkb, u16t* wvb, u16t* wob)
{
  long c = (long)blockIdx.x * 256 + threadIdx.x;
  const float* s; u16t* d; long o; bool perm = false;
  if (c < 2097152L)      { s = q; d = qx; o = c; }
  else if (c < 4194304L) { s = k; d = kx; o = c - 2097152L; perm = true; }
  else if (c < 6291456L) { s = v; d = vx; o = c - 4194304L; perm = true; }
  else {
    long wc_ = c - 6291456L;
    int wi = (int)(wc_ >> 18); o = wc_ & 262143L;
    s = wi == 0 ? wq : wi == 1 ? wk : wi == 2 ? wv : wo;
    d = wi == 0 ? wqb : wi == 1 ? wkb : wi == 2 ? wvb : wob;
  }
  long od = o;
  if (perm) {
    long dst = (long)map[o >> 8];          // 256 chunks of 4 elems per row
    int slot = (int)(dst & 2047);
    int bb = (int)(dst >> 11);
    int L = ((ntl[bb] << 6) + 127) & ~127; // proj blocks touch rows < L only
    if (slot >= L) return;                 // dead slot: nobody reads it
    od = dst * 256 + (o & 255);
  }
  f32x4 x = *(const f32x4*)(s + o * 4);
  u16x4 y; y[0]=f2bf(x[0]); y[1]=f2bf(x[1]); y[2]=f2bf(x[2]); y[3]=f2bf(x[3]);
  *(u16x4*)(d + od * 4) = y;
}

// ---------------- all-bf16 128x128 GEMM, C[m][n] = sum_k A[m][k]*W[n][k] ----------------
// LDS tiles are passed IN from the __global__ wrapper: declaring them inside this
// (multiply-instantiated) function made hipcc allocate one 32KB block PER template
// instantiation -- projs3 carried 64KB (R5 counters: LDS_Block_Size 65536,
// occupancy 13%, everything else idle). One shared allocation restores 4-5
// blocks/CU so co-resident blocks hide each other's barrier drains (m114).
template<int EPI, int MASKC>
__device__ __forceinline__ void gemm_bf(u16t* __restrict__ As, u16t* __restrict__ Bs,
                                        const u16t* __restrict__ A, const u16t* __restrict__ W,
                                        void* Op, const float* __restrict__ Rp, long ldc,
                                        const int* __restrict__ Mp, float oscale,
                                        long bM, long bN)
{
  const int t = threadIdx.x;
  const int lane = t & 63;
  const int w = t >> 6;
  const int wr = w >> 1, wc = w & 1;
  const int l15 = lane & 15, lhi = lane >> 4;

  f32x4 acc[4][4];
#pragma unroll
  for (int i = 0; i < 4; i++)
#pragma unroll
    for (int j = 0; j < 4; j++) acc[i][j] = f4zero();

  auto stg = [&](int buf, int k0) {
#pragma unroll
    for (int i = 0; i < 2; i++) {
      int idx = i * 256 + t;            // 512 chunks of 16B
      int row = idx >> 2, c4 = idx & 3;
      int ek = (c4 ^ (row & 3)) * 8;    // inverse-swizzled source column
      gload16(A + (bM + row) * (long)DM + k0 + ek, As + buf * 4096 + (i * 256 + w * 64) * 8);
      gload16(W + (bN + row) * (long)DM + k0 + ek, Bs + buf * 4096 + (i * 256 + w * 64) * 8);
    }
  };

  stg(0, 0);
  __syncthreads();
  int cur = 0;

  for (int k0 = 0; k0 < DM; k0 += 32) {
    if (k0 + 32 < DM) stg(cur ^ 1, k0 + 32);

    u16x8 af[4], bfv[4];
#pragma unroll
    for (int i = 0; i < 4; i++) {
      int ra = wr * 64 + i * 16 + l15;
      af[i]  = *(const u16x8*)((const char*)(As + cur * 4096) + ra * 64 + ((lhi ^ (ra & 3)) * 16));
      int rb = wc * 64 + i * 16 + l15;
      bfv[i] = *(const u16x8*)((const char*)(Bs + cur * 4096) + rb * 64 + ((lhi ^ (rb & 3)) * 16));
    }
#pragma unroll
    for (int i = 0; i < 4; i++)
#pragma unroll
      for (int j = 0; j < 4; j++)
        acc[i][j] = __builtin_amdgcn_mfma_f32_16x16x32_bf16(asbf(af[i]), asbf(bfv[j]), acc[i][j], 0, 0, 0);

    __syncthreads();
    cur ^= 1;
  }

#pragma unroll
  for (int i = 0; i < 4; i++) {
    long row0 = bM + wr * 64 + i * 16 + lhi * 4;
#pragma unroll
    for (int j = 0; j < 4; j++) {
      long col = bN + wc * 64 + j * 16 + l15;
      float mc = MASKC ? (float)Mp[col] * oscale : oscale;
#pragma unroll
      for (int r = 0; r < 4; r++) {
        long off = (row0 + r) * ldc + col;
        if (EPI == 0) ((u16t*)Op)[off] = f2bf(acc[i][j][r] * mc);
        else          ((float*)Op)[off] = acc[i][j][r] + Rp[off];
      }
    }
  }
}

#define SCLQ 0.1803368801111204f   // (1/sqrt(HD)) * log2(e): Q projection pre-scale (log2 domain)
#define GEMM_LDS_DECL  __shared__ u16t As[2][128 * 32]; __shared__ u16t Bs[2][128 * 32]

// V^T projection runs BEFORE qkproj in the FALLBACK path (qb aliases vx there).
// Inputs vx/kx already row-compacted; Mp = slot-ordered compacted mask.
// Early-exit: column blocks entirely beyond the live-tile boundary are dead.
__global__ __launch_bounds__(256) void vproj_t_kernel(
    const u16t* wvb, const u16t* vx, u16t* vtb, const int* cmask, const int* ntl)
{
  GEMM_LDS_DECL;
  long bN = (long)blockIdx.y * 128;
  if ((int)(bN & 2047) >= (ntl[bN >> 11] << 6)) return;
  gemm_bf<0, 1>(&As[0][0], &Bs[0][0], wvb, vx, vtb, nullptr, (long)MROWS, cmask, 1.0f,
                (long)blockIdx.x * 128, bN);
}

__global__ __launch_bounds__(256) void qkproj_kernel(
    const u16t* qx, const u16t* kx, const u16t* wqb, const u16t* wkb,
    u16t* qb, u16t* kbp, const int* ntl)
{
  GEMM_LDS_DECL;
  int z = blockIdx.z;
  if (z == 0)
    gemm_bf<0, 0>(&As[0][0], &Bs[0][0], qx, wqb, qb, nullptr, DM, nullptr, SCLQ,
                  (long)blockIdx.x * 128, (long)blockIdx.y * 128);
  else {
    long bM = (long)blockIdx.x * 128;
    if ((int)(bM & 2047) >= (ntl[bM >> 11] << 6)) return;
    gemm_bf<0, 0>(&As[0][0], &Bs[0][0], kx, wkb, kbp, nullptr, DM, nullptr, 1.0f,
                  bM, (long)blockIdx.y * 128);
  }
}

// Merged 3-projection dispatch -- ONLY legal when qb is a dedicated buffer
// (no vx alias; R7's race). z=0: V^T (masked), z=1: Q (scaled), z=2: K.
// K rows / V^T cols beyond each batch's live-tile boundary are read by nobody
// (attn visits ntl[b] tiles) -> early-exit those blocks.
__global__ __launch_bounds__(256) void projs3_kernel(
    const u16t* qx, const u16t* kx, const u16t* vx,
    const u16t* wqb, const u16t* wkb, const u16t* wvb,
    u16t* qb, u16t* kbp, u16t* vtb, const int* cmask, const int* ntl)
{
  GEMM_LDS_DECL;
  int z = blockIdx.z;
  if (z == 0) {
    long bN = (long)blockIdx.x * 128;
    if ((int)(bN & 2047) >= (ntl[bN >> 11] << 6)) return;
    gemm_bf<0, 1>(&As[0][0], &Bs[0][0], wvb, vx, vtb, nullptr, (long)MROWS, cmask, 1.0f,
                  (long)blockIdx.y * 128, bN);
  } else if (z == 1) {
    gemm_bf<0, 0>(&As[0][0], &Bs[0][0], qx, wqb, qb, nullptr, DM, nullptr, SCLQ,
                  (long)blockIdx.x * 128, (long)blockIdx.y * 128);
  } else {
    long bM = (long)blockIdx.x * 128;
    if ((int)(bM & 2047) >= (ntl[bM >> 11] << 6)) return;
    gemm_bf<0, 0>(&As[0][0], &Bs[0][0], kx, wkb, kbp, nullptr, DM, nullptr, 1.0f,
                  bM, (long)blockIdx.y * 128);
  }
}

__global__ __launch_bounds__(256) void outproj_gemm_kernel(
    const u16t* A, const u16t* Wo, float* O, const float* resid)
{
  GEMM_LDS_DECL;
  gemm_bf<1, 0>(&As[0][0], &Bs[0][0], A, Wo, O, resid, DM, nullptr, 1.0f,
                (long)blockIdx.x * 128, (long)blockIdx.y * 128);
}

// ---------------- flash attention: 32x32 swapped-QK, in-register softmax ----------------
// R11 base (256-row Q-tile, 512 threads / 8 waves) + R12: CONFLICT-FREE LDS LAYOUT.
// Diagnosis (R9/R11 invariance): attn is LDS-BW/conflict bound -- each wave reads
// the full 16KB K+V tile (16 x ds_read_b128); per-CU LDS cycles/tile ~2048 x 1.4
// conflict overhead matched the measured phase time, and was invariant to VALU cuts
// (R9) and block shape (R11). Old [64][64] tiles have 128B rows -> 8 slots -> 4-way
// bank conflict (the constant 4.39M counter). New layout: 256B logical rows packing
// 2 keys (or 2 V-dims), slot = (k&1)*8 + (d ^ ((k>>1)&7)):
//   write: chunk c holds key 2(c>>4)+((c>>3)&1), dim16 (c&7)^((c>>4)&7)
//   read:  byte = (k>>1)*256 + ((k&1)*8 + (d ^ ((k>>1)&7)))*16
// For any fragment, 32 lanes hit all 16 slots exactly 2x = FREE (m136). Bijection
// verified (XOR involution; (k>>1)&7 is kbi-invariant since 16 = 0 mod 8). Staging
// stays global_load_lds-linear with pre-swizzled SOURCE addresses (rule #21).
// MFMA/softmax/epilogue byte-identical to R11.
__global__ __launch_bounds__(512) void attn_kernel(
    const u16t* __restrict__ qb, const u16t* __restrict__ kb,
    const u16t* __restrict__ vt, const float* __restrict__ cmf,
    const int* __restrict__ ntl, u16t* __restrict__ ob)
{
  __shared__ u16t Kt[2][64 * 64];
  __shared__ u16t Vs[2][64 * 64];
  const int t = threadIdx.x;
  const int lane = t & 63, wv = t >> 6;        // wv 0..7
  const int l31 = lane & 31, hi = lane >> 5;
  const int bh = blockIdx.x, qt = blockIdx.y;  // grid (64, 8)
  const int b = bh >> 4, h = bh & 15;
  const int q0 = qt * 256;
  const int ktend = ntl[b] << 6;

  u16x8 qf[4];
  {
    long qrow = (long)b * SEQ + q0 + wv * 32 + l31;
#pragma unroll
    for (int ds = 0; ds < 4; ds++)
      qf[ds] = *(const u16x8*)(qb + qrow * (long)DM + h * HD + ds * 16 + hi * 8);
  }

  // tile-invariant LDS read offsets: 256B-row layout, slot XOR swizzle.
  // colX[c] serves QK (c = ds, row = key) and PV (c = ks, row = V-dim).
  const int rx = (l31 >> 1) & 7;
  int colX[4];
#pragma unroll
  for (int c = 0; c < 4; c++)
    colX[c] = (l31 >> 1) * 256 + ((l31 & 1) * 8 + ((2 * c + hi) ^ rx)) * 16;

  // all-ones bf16 B-fragment for the denominator MFMA
  u16x8 onesf;
#pragma unroll
  for (int j = 0; j < 8; j++) onesf[j] = 0x3F80;

  f32x16 oacc[2], lacc, z16;
#pragma unroll
  for (int r = 0; r < 16; r++) { oacc[0][r] = 0.f; oacc[1][r] = 0.f; lacc[r] = 0.f; z16[r] = 0.f; }

  // per-thread stage sources: 512 threads cover 512 K-chunks + 512 V-chunks.
  // chunk c = t: LDS row = c>>4; stores key/dim srow = 2*(c>>4)+((c>>3)&1),
  // dim16/key16 = (c&7) ^ ((c>>4)&7). LDS dest linear (wave base + lane*16B).
  int srow = 2 * (t >> 4) + ((t >> 3) & 1);
  int sek = ((t & 7) ^ ((t >> 4) & 7)) * 8;
  const u16t* gk0 = kb + ((long)b * SEQ + srow) * (long)DM + h * HD + sek;
  const u16t* gv0 = vt + ((long)h * HD + srow) * (long)MROWS + (long)b * SEQ + sek;

  auto stage = [&](int buf) {
    gload16(gk0, &Kt[buf][(wv * 64) * 8]);
    gload16(gv0, &Vs[buf][(wv * 64) * 8]);
    gk0 += 64 * DM; gv0 += 64;
  };

  stage(0);
  __syncthreads();
  int cur = 0;

  for (int kt0 = 0; kt0 < ktend; kt0 += 64) {
    const u16t* K0 = Kt[cur];
    const u16t* V0 = Vs[cur];
    const bool more = kt0 + 64 < ktend;

    f32x16 st[2];
    __builtin_amdgcn_s_setprio(1);
#pragma unroll
    for (int ds = 0; ds < 4; ds++) {
#pragma unroll
      for (int kbi = 0; kbi < 2; kbi++) {
        u16x8 kf = *(const u16x8*)((const char*)K0 + kbi * 4096 + colX[ds]);
        st[kbi] = __builtin_amdgcn_mfma_f32_32x32x16_bf16(asbf(kf), asbf(qf[ds]),
                                                          ds == 0 ? z16 : st[kbi], 0, 0, 0);
      }
    }
    __builtin_amdgcn_s_setprio(0);

    // stage next tile AFTER QK issue (off the ds_read critical path)
    if (more) stage(cur ^ 1);

    // tail tile only: per-key f32 masks, laid out to match e_j <-> key mapping.
    // group g = ks = kbi*2+s; ma_g covers keys base+{0..3}, mb_g keys base+{8..11},
    // base = kt0 + kbi*32 + 16s + 4hi.
    f32x4 ma0, mb0, ma1, mb1, ma2, mb2, ma3, mb3;
    if (!more) {
      const float* mfp = cmf + (long)b * SEQ + kt0 + 4 * hi;
      ma0 = *(const f32x4*)(mfp + 0);  mb0 = *(const f32x4*)(mfp + 8);
      ma1 = *(const f32x4*)(mfp + 16); mb1 = *(const f32x4*)(mfp + 24);
      ma2 = *(const f32x4*)(mfp + 32); mb2 = *(const f32x4*)(mfp + 40);
      ma3 = *(const f32x4*)(mfp + 48); mb3 = *(const f32x4*)(mfp + 56);
    }

    // PV with sm-split: exp of each 8-value group computed just before its MFMAs,
    // so trans-pipe exp of group ks+1 overlaps matrix-pipe MFMAs of group ks.
    __builtin_amdgcn_s_setprio(1);
#pragma unroll
    for (int ks = 0; ks < 4; ks++) {
      const int kbi = ks >> 1, s = ks & 1;
      float e0 = __builtin_amdgcn_exp2f(st[kbi][8*s+0]);
      float e1 = __builtin_amdgcn_exp2f(st[kbi][8*s+1]);
      float e2 = __builtin_amdgcn_exp2f(st[kbi][8*s+2]);
      float e3 = __builtin_amdgcn_exp2f(st[kbi][8*s+3]);
      float e4 = __builtin_amdgcn_exp2f(st[kbi][8*s+4]);
      float e5 = __builtin_amdgcn_exp2f(st[kbi][8*s+5]);
      float e6 = __builtin_amdgcn_exp2f(st[kbi][8*s+6]);
      float e7 = __builtin_amdgcn_exp2f(st[kbi][8*s+7]);
      if (!more) {  // tail: zero masked keys' P exactly (x1.0 / x0.0)
        f32x4 ma = ks == 0 ? ma0 : ks == 1 ? ma1 : ks == 2 ? ma2 : ma3;
        f32x4 mb = ks == 0 ? mb0 : ks == 1 ? mb1 : ks == 2 ? mb2 : mb3;
        e0 *= ma[0]; e1 *= ma[1]; e2 *= ma[2]; e3 *= ma[3];
        e4 *= mb[0]; e5 *= mb[1]; e6 *= mb[2]; e7 *= mb[3];
      }
      // permlane32_swap(x, y): x.hi32-lanes <-> y.lo32-lanes. x = a-pack, y = b-pack.
      // Verified identical to R6's shfl_xor+select path (R10/R12 pass).
      u32t x0 = packbf(e0, e1);
      u32t y0 = packbf(e4, e5);
      u32t x1 = packbf(e2, e3);
      u32t y1 = packbf(e6, e7);
      asm("v_permlane32_swap_b32 %0, %1" : "+v"(x0), "+v"(y0));
      asm("v_permlane32_swap_b32 %0, %1" : "+v"(x1), "+v"(y1));
      union { u32t u[4]; u16x8 v; } pf;
      pf.u[0] = x0; pf.u[1] = x1; pf.u[2] = y0; pf.u[3] = y1;
      bf16x8 pa = asbf(pf.v);

      lacc = __builtin_amdgcn_mfma_f32_32x32x16_bf16(pa, asbf(onesf), lacc, 0, 0, 0);
#pragma unroll
      for (int db = 0; db < 2; db++) {
        u16x8 vf = *(const u16x8*)((const char*)V0 + db * 4096 + colX[ks]);
        oacc[db] = __builtin_amdgcn_mfma_f32_32x32x16_bf16(pa, asbf(vf), oacc[db], 0, 0, 0);
      }
    }
    __builtin_amdgcn_s_setprio(0);

    __syncthreads();   // drains stage loads + publishes next buffer
    cur ^= 1;
  }

#pragma unroll
  for (int r = 0; r < 16; r++) {
    float inv = 1.0f / lacc[r];
    long s = (long)b * SEQ + q0 + wv * 32 + (r & 3) + 8 * (r >> 2) + 4 * hi;
#pragma unroll
    for (int db = 0; db < 2; db++)
      ob[s * (long)DM + h * HD + db * 32 + l31] = f2bf(oacc[db][r] * inv);
  }
}

// ---------------- layernorm (in-place) ----------------
__global__ __launch_bounds__(256) void ln_kernel(
    const float* __restrict__ x, const float* __restrict__ gam,
    const float* __restrict__ bet, float* __restrict__ out)
{
  __shared__ float red[8];
  const int row = blockIdx.x, t = threadIdx.x;
  const int w = t >> 6, lane = t & 63;
  const float* xr = x + (long)row * DM;
  f32x4 v = *(const f32x4*)(xr + t * 4);
  float s  = v[0] + v[1] + v[2] + v[3];
  float s2 = v[0]*v[0] + v[1]*v[1] + v[2]*v[2] + v[3]*v[3];
#pragma unroll
  for (int d = 1; d < 64; d <<= 1) {
    s  += __shfl_xor(s, d, 64);
    s2 += __shfl_xor(s2, d, 64);
  }
  if (lane == 0) { red[w] = s; red[4 + w] = s2; }
  __syncthreads();
  s  = red[0] + red[1] + red[2] + red[3];
  s2 = red[4] + red[5] + red[6] + red[7];
  float mu  = s * (1.f / DM);
  float var = s2 * (1.f / DM) - mu * mu;
  float rstd = rsqrtf(var + 1e-5f);
  f32x4 g = *(const f32x4*)(gam + t * 4);
  f32x4 bb = *(const f32x4*)(bet + t * 4);
  f32x4 o;
#pragma unroll
  for (int j = 0; j < 4; j++) o[j] = (v[j] - mu) * rstd * g[j] + bb[j];
  *(f32x4*)(out + (long)row * DM + t * 4) = o;
}

extern "C" void kernel_launch(void* const* d_in, const int* in_sizes, int n_in,
                              void* d_out, int out_size, void* d_ws, size_t ws_size,
                              hipStream_t stream)
{
  const float* query = (const float*)d_in[0];
  const float* key   = (const float*)d_in[1];
  const float* value = (const float*)d_in[2];
  const int*   msk   = (const int*)d_in[3];
  const float* Wq    = (const float*)d_in[4];
  const float* Wk    = (const float*)d_in[5];
  const float* Wv    = (const float*)d_in[6];
  const float* Wo    = (const float*)d_in[7];
  const float* gam   = (const float*)d_in[8];
  const float* bet   = (const float*)d_in[9];
  float* out = (float*)d_out;

  const long SZ = (long)MROWS * DM;     // 8.4M elements
  const long WS = (long)DM * DM;        // 1M elements
  u16t* qx  = (u16t*)d_out;             // bf16 query [8192][1024] (d_out as scratch)
  u16t* kx  = qx + SZ;                  // bf16 key (row-compacted)
  u16t* vx  = (u16t*)d_ws;              // bf16 value (row-compacted)
  u16t* vtb = vx + SZ;                  // bf16 masked V^T [1024][8192] (compacted cols)
  u16t* kbp = vtb + SZ;                 // bf16 projected k (compacted rows)
  u16t* wqb = kbp + SZ;                 // bf16 weights
  u16t* wkb = wqb + WS;
  u16t* wvb = wkb + WS;
  u16t* wob = wvb + WS;
  int*  map = (int*)(wob + WS);         // stable-partition destination rows [8192]
  int*  cmask = map + 8192;             // int compacted mask [8192] (slot order)
  float* cmf = (float*)(cmask + 8192);  // f32 compacted mask [8192] (attn tail)
  int*  ntl = (int*)(cmf + 8192);       // per-batch live-tile counts [4]
  u16t* ws_end = (u16t*)(ntl + 4);
  // If ws has room, give projected-q its own buffer -> all three projections
  // become independent and merge into ONE dispatch (no vx alias race).
  size_t used_bytes = (size_t)((char*)ws_end - (char*)d_ws);
  bool big = ws_size >= used_bytes + (size_t)SZ * 2;
  u16t* qb = big ? ws_end : vx;         // fallback: qb aliases vx (R13 path)
  u16t* ab = qb;                        // attn out overwrites qb
  float* xres = out;

  scan_kernel<<<dim3(4), 256, 0, stream>>>(msk, map, cmask, cmf, ntl);
  cvt_kernel<<<dim3(28672), 256, 0, stream>>>(query, key, value, Wq, Wk, Wv, Wo, map, ntl,
                                              qx, kx, vx, wqb, wkb, wvb, wob);
  if (big) {
    projs3_kernel<<<dim3(64, 8, 3), 256, 0, stream>>>(qx, kx, vx, wqb, wkb, wvb,
                                                      qb, kbp, vtb, cmask, ntl);
  } else {
    vproj_t_kernel<<<dim3(8, 64), 256, 0, stream>>>(wvb, vx, vtb, cmask, ntl); // reads vx
    qkproj_kernel<<<dim3(64, 8, 2), 256, 0, stream>>>(qx, kx, wqb, wkb, qb, kbp, ntl);
  }
  attn_kernel<<<dim3(64, 8), 512, 0, stream>>>(qb, kbp, vtb, cmf, ntl, ab);
  outproj_gemm_kernel<<<dim3(64, 8), 256, 0, stream>>>(ab, wob, xres, query);
  ln_kernel<<<dim3(MROWS), 256, 0, stream>>>(xres, gam, bet, out);
}

// Round 13
// 194.908 us; speedup vs baseline: 1.1572x; 1.0227x over previous
//
#include <hip/hip_runtime.h>

typedef unsigned short u16t;
typedef unsigned int   u32t;
typedef float  f32x4  __attribute__((ext_vector_type(4)));
typedef float  f32x16 __attribute__((ext_vector_type(16)));
typedef __bf16 bf16x8 __attribute__((ext_vector_type(8)));
typedef u16t   u16x4  __attribute__((ext_vector_type(4)));
typedef u16t   u16x8  __attribute__((ext_vector_type(8)));

#define DM    1024
#define SEQ   2048
#define NH    16
#define HD    64
#define MROWS 8192   // B*S

static __device__ __forceinline__ u16t f2bf(float f) {
  union { __bf16 b; u16t u; } c; c.b = (__bf16)f; return c.u;
}
static __device__ __forceinline__ u32t packbf(float lo, float hi) {
  union { u16t u[2]; u32t v; } c; c.u[0] = f2bf(lo); c.u[1] = f2bf(hi); return c.v;
}
static __device__ __forceinline__ bf16x8 asbf(u16x8 v) {
  union { u16x8 u; bf16x8 b; } c; c.u = v; return c.b;
}
static __device__ __forceinline__ f32x4 f4zero() {
  f32x4 z; z[0]=0.f; z[1]=0.f; z[2]=0.f; z[3]=0.f; return z;
}
static __device__ __forceinline__ void gload16(const u16t* g, u16t* l) {
  __builtin_amdgcn_global_load_lds(
      (const __attribute__((address_space(1))) unsigned int*)g,
      (__attribute__((address_space(3))) unsigned int*)l, 16, 0, 0);
}

// ---------------- per-batch stable-partition scan ----------------
// For each batch b: unmasked key positions -> slots [0, nu), masked -> [nu, 2048).
// map[b*2048+s]   = destination slot (global row index) for source key s,
// cmask[slot]     = 1 if slot < nu else 0 (int, slot order, for V-proj epilogue),
// cmf[slot]       = same as f32 (for attn's tail-tile exp masking),
// ntl[b]          = ceil(nu/64) = number of 64-key attn tiles containing live keys.
__global__ __launch_bounds__(256) void scan_kernel(
    const int* __restrict__ msk, int* __restrict__ map,
    int* __restrict__ cmask, float* __restrict__ cmf, int* __restrict__ ntl)
{
  const int b = blockIdx.x, t = threadIdx.x;
  const int lane = t & 63, w = t >> 6;
  const int base = b * 2048 + t * 8;
  int4 a0 = ((const int4*)(msk + base))[0];
  int4 a1 = ((const int4*)(msk + base))[1];
  int mv[8] = { a0.x, a0.y, a0.z, a0.w, a1.x, a1.y, a1.z, a1.w };
  int ps = 0;
#pragma unroll
  for (int i = 0; i < 8; i++) ps += mv[i];
  int sc = ps;                       // inclusive scan of per-thread sums
#pragma unroll
  for (int d = 1; d < 64; d <<= 1) {
    int o = __shfl_up(sc, d, 64);
    if (lane >= d) sc += o;
  }
  __shared__ int wsum[4];
  if (lane == 63) wsum[w] = sc;
  __syncthreads();
  int nu = wsum[0] + wsum[1] + wsum[2] + wsum[3];
  int woff = 0;
  for (int i = 0; i < w; i++) woff += wsum[i];
  int u = woff + sc - ps;            // unmasked count before this thread's first elem
#pragma unroll
  for (int i = 0; i < 8; i++) {
    int s = t * 8 + i;
    int slot = mv[i] ? u : nu + (s - u);
    map[b * 2048 + s] = b * 2048 + slot;
    u += mv[i];
  }
#pragma unroll
  for (int i = 0; i < 8; i++) {
    int s = t * 8 + i;
    int live = s < nu ? 1 : 0;
    cmask[b * 2048 + s] = live;
    cmf[b * 2048 + s] = (float)live;
  }
  if (t == 0) ntl[b] = (nu + 63) >> 6;
}

// ---------------- bf16 conversion prepass (bandwidth-bound) ----------------
// K and V input rows are written PERMUTED (stable partition by mask): each 2KB
// row lands at map[row]. Stores stay wave-coalesced (row-granular scatter only).
// Rows whose destination slot lies beyond L[b] = ceil(ntl*64/128)*128 are read
// by NO downstream block (projection early-exit) -> skip load+store entirely.
__global__ __launch_bounds__(256) void cvt_kernel(
    const float* __restrict__ q, const float* __restrict__ k, const float* __restrict__ v,
    const float* __restrict__ wq, const float* __restrict__ wk,
    const float* __restrict__ wv, const float* __restrict__ wo,
    const int* __restrict__ map, const int* __restrict__ ntl,
    u16t* qx, u16t* kx, u16t* vx,
    u16t* wqb, u16t* wkb, u16t* wvb, u16t* wob)
{
  long c = (long)blockIdx.x * 256 + threadIdx.x;
  const float* s; u16t* d; long o; bool perm = false;
  if (c < 2097152L)      { s = q; d = qx; o = c; }
  else if (c < 4194304L) { s = k; d = kx; o = c - 2097152L; perm = true; }
  else if (c < 6291456L) { s = v; d = vx; o = c - 4194304L; perm = true; }
  else {
    long wc_ = c - 6291456L;
    int wi = (int)(wc_ >> 18); o = wc_ & 262143L;
    s = wi == 0 ? wq : wi == 1 ? wk : wi == 2 ? wv : wo;
    d = wi == 0 ? wqb : wi == 1 ? wkb : wi == 2 ? wvb : wob;
  }
  long od = o;
  if (perm) {
    long dst = (long)map[o >> 8];          // 256 chunks of 4 elems per row
    int slot = (int)(dst & 2047);
    int bb = (int)(dst >> 11);
    int L = ((ntl[bb] << 6) + 127) & ~127; // proj blocks touch rows < L only
    if (slot >= L) return;                 // dead slot: nobody reads it
    od = dst * 256 + (o & 255);
  }
  f32x4 x = *(const f32x4*)(s + o * 4);
  u16x4 y; y[0]=f2bf(x[0]); y[1]=f2bf(x[1]); y[2]=f2bf(x[2]); y[3]=f2bf(x[3]);
  *(u16x4*)(d + od * 4) = y;
}

// ---------------- all-bf16 128x128 GEMM, C[m][n] = sum_k A[m][k]*W[n][k] ----------------
// R13: 3-buffer K-pipeline with COUNTED vmcnt (T3/T4-lite). Diagnosis: projs3 at
// 66us showed MfmaUtil 22 / VALU 10 / HBM 16 -- the 2-buffer __syncthreads drains
// the same-step global_load_lds to vmcnt(0) every k-step (~1160 cyc/step vs ~150
// of issued work), and unlike attn there is no VALU work to fill the gap. Now
// stage runs 2 steps ahead; each step waits vmcnt(4) (= loads issued after the
// needed tile: exactly one stage of 4/thread) + raw s_barrier. stg is issued
// AFTER the barrier so the writer of buf[(i+2)%3] cannot race readers of the
// same buffer at step i-1 (they finished before barrier i). Last step peeled
// with vmcnt(0). LDS 48KB (3 blocks/CU): acceptable because there is nothing
// co-resident to lose (VALU 10%). LDS tiles passed in from wrappers (R6: one
// allocation per kernel, not per template instantiation).
template<int EPI, int MASKC>
__device__ __forceinline__ void gemm_bf(u16t* __restrict__ As, u16t* __restrict__ Bs,
                                        const u16t* __restrict__ A, const u16t* __restrict__ W,
                                        void* Op, const float* __restrict__ Rp, long ldc,
                                        const int* __restrict__ Mp, float oscale,
                                        long bM, long bN)
{
  const int t = threadIdx.x;
  const int lane = t & 63;
  const int w = t >> 6;
  const int wr = w >> 1, wc = w & 1;
  const int l15 = lane & 15, lhi = lane >> 4;

  f32x4 acc[4][4];
#pragma unroll
  for (int i = 0; i < 4; i++)
#pragma unroll
    for (int j = 0; j < 4; j++) acc[i][j] = f4zero();

  auto stg = [&](int buf, int k0) {
#pragma unroll
    for (int i = 0; i < 2; i++) {
      int idx = i * 256 + t;            // 512 chunks of 16B
      int row = idx >> 2, c4 = idx & 3;
      int ek = (c4 ^ (row & 3)) * 8;    // inverse-swizzled source column
      gload16(A + (bM + row) * (long)DM + k0 + ek, As + buf * 4096 + (i * 256 + w * 64) * 8);
      gload16(W + (bN + row) * (long)DM + k0 + ek, Bs + buf * 4096 + (i * 256 + w * 64) * 8);
    }
  };

  auto compute = [&](int cur) {
    u16x8 af[4], bfv[4];
#pragma unroll
    for (int i = 0; i < 4; i++) {
      int ra = wr * 64 + i * 16 + l15;
      af[i]  = *(const u16x8*)((const char*)(As + cur * 4096) + ra * 64 + ((lhi ^ (ra & 3)) * 16));
      int rb = wc * 64 + i * 16 + l15;
      bfv[i] = *(const u16x8*)((const char*)(Bs + cur * 4096) + rb * 64 + ((lhi ^ (rb & 3)) * 16));
    }
#pragma unroll
    for (int i = 0; i < 4; i++)
#pragma unroll
      for (int j = 0; j < 4; j++)
        acc[i][j] = __builtin_amdgcn_mfma_f32_16x16x32_bf16(asbf(af[i]), asbf(bfv[j]), acc[i][j], 0, 0, 0);
  };

  // prologue: 2 tiles in flight (8 vmem ops/thread)
  stg(0, 0);
  stg(1, 32);
  int cur = 0;

  // steps 0..30: wait for tile i (4 ops issued after it) -> barrier -> stage i+2
  for (int i = 0; i < 31; i++) {
    asm volatile("s_waitcnt vmcnt(4)" ::: "memory");
    __builtin_amdgcn_sched_barrier(0);
    __builtin_amdgcn_s_barrier();
    if (i < 30) {
      int bs = cur + 2; if (bs >= 3) bs -= 3;
      stg(bs, (i + 2) * 32);
    }
    compute(cur);
    cur = cur + 1; if (cur >= 3) cur = 0;
  }
  // step 31 (last): nothing issued after its stage -> full drain
  asm volatile("s_waitcnt vmcnt(0)" ::: "memory");
  __builtin_amdgcn_sched_barrier(0);
  __builtin_amdgcn_s_barrier();
  compute(cur);

#pragma unroll
  for (int i = 0; i < 4; i++) {
    long row0 = bM + wr * 64 + i * 16 + lhi * 4;
#pragma unroll
    for (int j = 0; j < 4; j++) {
      long col = bN + wc * 64 + j * 16 + l15;
      float mc = MASKC ? (float)Mp[col] * oscale : oscale;
#pragma unroll
      for (int r = 0; r < 4; r++) {
        long off = (row0 + r) * ldc + col;
        if (EPI == 0) ((u16t*)Op)[off] = f2bf(acc[i][j][r] * mc);
        else          ((float*)Op)[off] = acc[i][j][r] + Rp[off];
      }
    }
  }
}

#define SCLQ 0.1803368801111204f   // (1/sqrt(HD)) * log2(e): Q projection pre-scale (log2 domain)
#define GEMM_LDS_DECL  __shared__ u16t As[3][128 * 32]; __shared__ u16t Bs[3][128 * 32]

// V^T projection runs BEFORE qkproj in the FALLBACK path (qb aliases vx there).
// Inputs vx/kx already row-compacted; Mp = slot-ordered compacted mask.
// Early-exit: column blocks entirely beyond the live-tile boundary are dead.
__global__ __launch_bounds__(256) void vproj_t_kernel(
    const u16t* wvb, const u16t* vx, u16t* vtb, const int* cmask, const int* ntl)
{
  GEMM_LDS_DECL;
  long bN = (long)blockIdx.y * 128;
  if ((int)(bN & 2047) >= (ntl[bN >> 11] << 6)) return;
  gemm_bf<0, 1>(&As[0][0], &Bs[0][0], wvb, vx, vtb, nullptr, (long)MROWS, cmask, 1.0f,
                (long)blockIdx.x * 128, bN);
}

__global__ __launch_bounds__(256) void qkproj_kernel(
    const u16t* qx, const u16t* kx, const u16t* wqb, const u16t* wkb,
    u16t* qb, u16t* kbp, const int* ntl)
{
  GEMM_LDS_DECL;
  int z = blockIdx.z;
  if (z == 0)
    gemm_bf<0, 0>(&As[0][0], &Bs[0][0], qx, wqb, qb, nullptr, DM, nullptr, SCLQ,
                  (long)blockIdx.x * 128, (long)blockIdx.y * 128);
  else {
    long bM = (long)blockIdx.x * 128;
    if ((int)(bM & 2047) >= (ntl[bM >> 11] << 6)) return;
    gemm_bf<0, 0>(&As[0][0], &Bs[0][0], kx, wkb, kbp, nullptr, DM, nullptr, 1.0f,
                  bM, (long)blockIdx.y * 128);
  }
}

// Merged 3-projection dispatch -- ONLY legal when qb is a dedicated buffer
// (no vx alias; R7's race). z=0: V^T (masked), z=1: Q (scaled), z=2: K.
// K rows / V^T cols beyond each batch's live-tile boundary are read by nobody
// (attn visits ntl[b] tiles) -> early-exit those blocks.
__global__ __launch_bounds__(256) void projs3_kernel(
    const u16t* qx, const u16t* kx, const u16t* vx,
    const u16t* wqb, const u16t* wkb, const u16t* wvb,
    u16t* qb, u16t* kbp, u16t* vtb, const int* cmask, const int* ntl)
{
  GEMM_LDS_DECL;
  int z = blockIdx.z;
  if (z == 0) {
    long bN = (long)blockIdx.x * 128;
    if ((int)(bN & 2047) >= (ntl[bN >> 11] << 6)) return;
    gemm_bf<0, 1>(&As[0][0], &Bs[0][0], wvb, vx, vtb, nullptr, (long)MROWS, cmask, 1.0f,
                  (long)blockIdx.y * 128, bN);
  } else if (z == 1) {
    gemm_bf<0, 0>(&As[0][0], &Bs[0][0], qx, wqb, qb, nullptr, DM, nullptr, SCLQ,
                  (long)blockIdx.x * 128, (long)blockIdx.y * 128);
  } else {
    long bM = (long)blockIdx.x * 128;
    if ((int)(bM & 2047) >= (ntl[bM >> 11] << 6)) return;
    gemm_bf<0, 0>(&As[0][0], &Bs[0][0], kx, wkb, kbp, nullptr, DM, nullptr, 1.0f,
                  bM, (long)blockIdx.y * 128);
  }
}

__global__ __launch_bounds__(256) void outproj_gemm_kernel(
    const u16t* A, const u16t* Wo, float* O, const float* resid)
{
  GEMM_LDS_DECL;
  gemm_bf<1, 0>(&As[0][0], &Bs[0][0], A, Wo, O, resid, DM, nullptr, 1.0f,
                (long)blockIdx.x * 128, (long)blockIdx.y * 128);
}

// ---------------- flash attention: 32x32 swapped-QK, in-register softmax ----------------
// R12 body (verified 66.4us, bank-conflict ZERO): 256-row Q-tile, 512 threads /
// 8 waves; compacted keys; no max-tracking; ones-fragment lacc + tail-tile f32
// masking; conflict-free 256B-row XOR LDS layout:
//   write: chunk c holds key 2(c>>4)+((c>>3)&1), dim16 (c&7)^((c>>4)&7)
//   read:  byte = (k>>1)*256 + ((k&1)*8 + (d ^ ((k>>1)&7)))*16
__global__ __launch_bounds__(512) void attn_kernel(
    const u16t* __restrict__ qb, const u16t* __restrict__ kb,
    const u16t* __restrict__ vt, const float* __restrict__ cmf,
    const int* __restrict__ ntl, u16t* __restrict__ ob)
{
  __shared__ u16t Kt[2][64 * 64];
  __shared__ u16t Vs[2][64 * 64];
  const int t = threadIdx.x;
  const int lane = t & 63, wv = t >> 6;        // wv 0..7
  const int l31 = lane & 31, hi = lane >> 5;
  const int bh = blockIdx.x, qt = blockIdx.y;  // grid (64, 8)
  const int b = bh >> 4, h = bh & 15;
  const int q0 = qt * 256;
  const int ktend = ntl[b] << 6;

  u16x8 qf[4];
  {
    long qrow = (long)b * SEQ + q0 + wv * 32 + l31;
#pragma unroll
    for (int ds = 0; ds < 4; ds++)
      qf[ds] = *(const u16x8*)(qb + qrow * (long)DM + h * HD + ds * 16 + hi * 8);
  }

  // tile-invariant LDS read offsets: 256B-row layout, slot XOR swizzle.
  const int rx = (l31 >> 1) & 7;
  int colX[4];
#pragma unroll
  for (int c = 0; c < 4; c++)
    colX[c] = (l31 >> 1) * 256 + ((l31 & 1) * 8 + ((2 * c + hi) ^ rx)) * 16;

  // all-ones bf16 B-fragment for the denominator MFMA
  u16x8 onesf;
#pragma unroll
  for (int j = 0; j < 8; j++) onesf[j] = 0x3F80;

  f32x16 oacc[2], lacc, z16;
#pragma unroll
  for (int r = 0; r < 16; r++) { oacc[0][r] = 0.f; oacc[1][r] = 0.f; lacc[r] = 0.f; z16[r] = 0.f; }

  // per-thread stage sources: 512 threads cover 512 K-chunks + 512 V-chunks.
  int srow = 2 * (t >> 4) + ((t >> 3) & 1);
  int sek = ((t & 7) ^ ((t >> 4) & 7)) * 8;
  const u16t* gk0 = kb + ((long)b * SEQ + srow) * (long)DM + h * HD + sek;
  const u16t* gv0 = vt + ((long)h * HD + srow) * (long)MROWS + (long)b * SEQ + sek;

  auto stage = [&](int buf) {
    gload16(gk0, &Kt[buf][(wv * 64) * 8]);
    gload16(gv0, &Vs[buf][(wv * 64) * 8]);
    gk0 += 64 * DM; gv0 += 64;
  };

  stage(0);
  __syncthreads();
  int cur = 0;

  for (int kt0 = 0; kt0 < ktend; kt0 += 64) {
    const u16t* K0 = Kt[cur];
    const u16t* V0 = Vs[cur];
    const bool more = kt0 + 64 < ktend;

    f32x16 st[2];
    __builtin_amdgcn_s_setprio(1);
#pragma unroll
    for (int ds = 0; ds < 4; ds++) {
#pragma unroll
      for (int kbi = 0; kbi < 2; kbi++) {
        u16x8 kf = *(const u16x8*)((const char*)K0 + kbi * 4096 + colX[ds]);
        st[kbi] = __builtin_amdgcn_mfma_f32_32x32x16_bf16(asbf(kf), asbf(qf[ds]),
                                                          ds == 0 ? z16 : st[kbi], 0, 0, 0);
      }
    }
    __builtin_amdgcn_s_setprio(0);

    // stage next tile AFTER QK issue (off the ds_read critical path)
    if (more) stage(cur ^ 1);

    // tail tile only: per-key f32 masks, laid out to match e_j <-> key mapping.
    f32x4 ma0, mb0, ma1, mb1, ma2, mb2, ma3, mb3;
    if (!more) {
      const float* mfp = cmf + (long)b * SEQ + kt0 + 4 * hi;
      ma0 = *(const f32x4*)(mfp + 0);  mb0 = *(const f32x4*)(mfp + 8);
      ma1 = *(const f32x4*)(mfp + 16); mb1 = *(const f32x4*)(mfp + 24);
      ma2 = *(const f32x4*)(mfp + 32); mb2 = *(const f32x4*)(mfp + 40);
      ma3 = *(const f32x4*)(mfp + 48); mb3 = *(const f32x4*)(mfp + 56);
    }

    // PV with sm-split: exp of each 8-value group computed just before its MFMAs.
    __builtin_amdgcn_s_setprio(1);
#pragma unroll
    for (int ks = 0; ks < 4; ks++) {
      const int kbi = ks >> 1, s = ks & 1;
      float e0 = __builtin_amdgcn_exp2f(st[kbi][8*s+0]);
      float e1 = __builtin_amdgcn_exp2f(st[kbi][8*s+1]);
      float e2 = __builtin_amdgcn_exp2f(st[kbi][8*s+2]);
      float e3 = __builtin_amdgcn_exp2f(st[kbi][8*s+3]);
      float e4 = __builtin_amdgcn_exp2f(st[kbi][8*s+4]);
      float e5 = __builtin_amdgcn_exp2f(st[kbi][8*s+5]);
      float e6 = __builtin_amdgcn_exp2f(st[kbi][8*s+6]);
      float e7 = __builtin_amdgcn_exp2f(st[kbi][8*s+7]);
      if (!more) {  // tail: zero masked keys' P exactly (x1.0 / x0.0)
        f32x4 ma = ks == 0 ? ma0 : ks == 1 ? ma1 : ks == 2 ? ma2 : ma3;
        f32x4 mb = ks == 0 ? mb0 : ks == 1 ? mb1 : ks == 2 ? mb2 : mb3;
        e0 *= ma[0]; e1 *= ma[1]; e2 *= ma[2]; e3 *= ma[3];
        e4 *= mb[0]; e5 *= mb[1]; e6 *= mb[2]; e7 *= mb[3];
      }
      u32t x0 = packbf(e0, e1);
      u32t y0 = packbf(e4, e5);
      u32t x1 = packbf(e2, e3);
      u32t y1 = packbf(e6, e7);
      asm("v_permlane32_swap_b32 %0, %1" : "+v"(x0), "+v"(y0));
      asm("v_permlane32_swap_b32 %0, %1" : "+v"(x1), "+v"(y1));
      union { u32t u[4]; u16x8 v; } pf;
      pf.u[0] = x0; pf.u[1] = x1; pf.u[2] = y0; pf.u[3] = y1;
      bf16x8 pa = asbf(pf.v);

      lacc = __builtin_amdgcn_mfma_f32_32x32x16_bf16(pa, asbf(onesf), lacc, 0, 0, 0);
#pragma unroll
      for (int db = 0; db < 2; db++) {
        u16x8 vf = *(const u16x8*)((const char*)V0 + db * 4096 + colX[ks]);
        oacc[db] = __builtin_amdgcn_mfma_f32_32x32x16_bf16(pa, asbf(vf), oacc[db], 0, 0, 0);
      }
    }
    __builtin_amdgcn_s_setprio(0);

    __syncthreads();   // drains stage loads + publishes next buffer
    cur ^= 1;
  }

#pragma unroll
  for (int r = 0; r < 16; r++) {
    float inv = 1.0f / lacc[r];
    long s = (long)b * SEQ + q0 + wv * 32 + (r & 3) + 8 * (r >> 2) + 4 * hi;
#pragma unroll
    for (int db = 0; db < 2; db++)
      ob[s * (long)DM + h * HD + db * 32 + l31] = f2bf(oacc[db][r] * inv);
  }
}

// ---------------- layernorm (in-place) ----------------
__global__ __launch_bounds__(256) void ln_kernel(
    const float* __restrict__ x, const float* __restrict__ gam,
    const float* __restrict__ bet, float* __restrict__ out)
{
  __shared__ float red[8];
  const int row = blockIdx.x, t = threadIdx.x;
  const int w = t >> 6, lane = t & 63;
  const float* xr = x + (long)row * DM;
  f32x4 v = *(const f32x4*)(xr + t * 4);
  float s  = v[0] + v[1] + v[2] + v[3];
  float s2 = v[0]*v[0] + v[1]*v[1] + v[2]*v[2] + v[3]*v[3];
#pragma unroll
  for (int d = 1; d < 64; d <<= 1) {
    s  += __shfl_xor(s, d, 64);
    s2 += __shfl_xor(s2, d, 64);
  }
  if (lane == 0) { red[w] = s; red[4 + w] = s2; }
  __syncthreads();
  s  = red[0] + red[1] + red[2] + red[3];
  s2 = red[4] + red[5] + red[6] + red[7];
  float mu  = s * (1.f / DM);
  float var = s2 * (1.f / DM) - mu * mu;
  float rstd = rsqrtf(var + 1e-5f);
  f32x4 g = *(const f32x4*)(gam + t * 4);
  f32x4 bb = *(const f32x4*)(bet + t * 4);
  f32x4 o;
#pragma unroll
  for (int j = 0; j < 4; j++) o[j] = (v[j] - mu) * rstd * g[j] + bb[j];
  *(f32x4*)(out + (long)row * DM + t * 4) = o;
}

extern "C" void kernel_launch(void* const* d_in, const int* in_sizes, int n_in,
                              void* d_out, int out_size, void* d_ws, size_t ws_size,
                              hipStream_t stream)
{
  const float* query = (const float*)d_in[0];
  const float* key   = (const float*)d_in[1];
  const float* value = (const float*)d_in[2];
  const int*   msk   = (const int*)d_in[3];
  const float* Wq    = (const float*)d_in[4];
  const float* Wk    = (const float*)d_in[5];
  const float* Wv    = (const float*)d_in[6];
  const float* Wo    = (const float*)d_in[7];
  const float* gam   = (const float*)d_in[8];
  const float* bet   = (const float*)d_in[9];
  float* out = (float*)d_out;

  const long SZ = (long)MROWS * DM;     // 8.4M elements
  const long WS = (long)DM * DM;        // 1M elements
  u16t* qx  = (u16t*)d_out;             // bf16 query [8192][1024] (d_out as scratch)
  u16t* kx  = qx + SZ;                  // bf16 key (row-compacted)
  u16t* vx  = (u16t*)d_ws;              // bf16 value (row-compacted)
  u16t* vtb = vx + SZ;                  // bf16 masked V^T [1024][8192] (compacted cols)
  u16t* kbp = vtb + SZ;                 // bf16 projected k (compacted rows)
  u16t* wqb = kbp + SZ;                 // bf16 weights
  u16t* wkb = wqb + WS;
  u16t* wvb = wkb + WS;
  u16t* wob = wvb + WS;
  int*  map = (int*)(wob + WS);         // stable-partition destination rows [8192]
  int*  cmask = map + 8192;             // int compacted mask [8192] (slot order)
  float* cmf = (float*)(cmask + 8192);  // f32 compacted mask [8192] (attn tail)
  int*  ntl = (int*)(cmf + 8192);       // per-batch live-tile counts [4]
  u16t* ws_end = (u16t*)(ntl + 4);
  // If ws has room, give projected-q its own buffer -> all three projections
  // become independent and merge into ONE dispatch (no vx alias race).
  size_t used_bytes = (size_t)((char*)ws_end - (char*)d_ws);
  bool big = ws_size >= used_bytes + (size_t)SZ * 2;
  u16t* qb = big ? ws_end : vx;         // fallback: qb aliases vx (R13 path)
  u16t* ab = qb;                        // attn out overwrites qb
  float* xres = out;

  scan_kernel<<<dim3(4), 256, 0, stream>>>(msk, map, cmask, cmf, ntl);
  cvt_kernel<<<dim3(28672), 256, 0, stream>>>(query, key, value, Wq, Wk, Wv, Wo, map, ntl,
                                              qx, kx, vx, wqb, wkb, wvb, wob);
  if (big) {
    projs3_kernel<<<dim3(64, 8, 3), 256, 0, stream>>>(qx, kx, vx, wqb, wkb, wvb,
                                                      qb, kbp, vtb, cmask, ntl);
  } else {
    vproj_t_kernel<<<dim3(8, 64), 256, 0, stream>>>(wvb, vx, vtb, cmask, ntl); // reads vx
    qkproj_kernel<<<dim3(64, 8, 2), 256, 0, stream>>>(qx, kx, wqb, wkb, qb, kbp, ntl);
  }
  attn_kernel<<<dim3(64, 8), 512, 0, stream>>>(qb, kbp, vtb, cmf, ntl, ab);
  outproj_gemm_kernel<<<dim3(64, 8), 256, 0, stream>>>(ab, wob, xres, query);
  ln_kernel<<<dim3(MROWS), 256, 0, stream>>>(xres, gam, bet, out);
}